// Round 3
// baseline (700.095 us; speedup 1.0000x reference)
//
#include <hip/hip_runtime.h>
#include <hip/hip_bf16.h>

typedef __attribute__((ext_vector_type(8))) __bf16 bf16x8;
typedef __attribute__((ext_vector_type(4))) float f32x4;

#define DEV static __device__ __forceinline__

#define BAR() asm volatile("s_barrier" ::: "memory")
#define LGKM0() asm volatile("s_waitcnt lgkmcnt(0)" ::: "memory")
#define VMCNT4() asm volatile("s_waitcnt vmcnt(4)" ::: "memory")
#define VMCNT0() asm volatile("s_waitcnt vmcnt(0)" ::: "memory")

DEV void load_lds16(const void* g, void* l) {
  __builtin_amdgcn_global_load_lds(
      (const __attribute__((address_space(1))) unsigned int*)g,
      (__attribute__((address_space(3))) unsigned int*)l, 16, 0, 0);
}

DEV unsigned short bf16bits(float v) {
  __hip_bfloat16 h = __float2bfloat16(v);
  return __builtin_bit_cast(unsigned short, h);
}

// swizzled LDS read: half = 128x64 bf16 (128B rows); data for (row, colbyte)
// lives at byte (row*128 + (colbyte ^ ((row&7)<<4))). Staging pre-applies the
// same XOR on the GLOBAL source so LDS dest stays linear (global_load_lds).
DEV bf16x8 rdfrag(const unsigned short* half, int row, int ks, int l) {
  const int cb = (((ks << 6) | ((l >> 4) << 4)) ^ ((l & 7) << 4));
  return *(const bf16x8*)((const char*)half + row * 128 + cb);
}

struct OffN { unsigned long long a[12], b[12], c[12]; };

enum { EPI_BF16 = 0, EPI_F32 = 1, EPI_LEAKY = 2, EPI_QKV = 3 };
enum { MODE_PLAIN = 0, MODE_SCORES = 1, MODE_PV = 2 };

// ---------------- 256x256 deep-pipelined GEMM (8 waves, BK=64) ----------------
// C[M][N] = A[M][K] * BT[N][K]^T + bias. 4 quadrant-phases per K-tile, 1
// half-tile staged per phase, vmcnt(4) once per K-tile (counted, never 0 in
// steady state). LDS 128KiB: [dbuf][half][128*64] per operand.
template<int EPI, int MODE>
__global__ __launch_bounds__(512, 2) void k_gemm256(
    const unsigned short* __restrict__ Abase, long lda,
    const unsigned short* __restrict__ Bbase, long ldb,
    const float* __restrict__ bias,
    void* __restrict__ Cbase, long ldc,
    int M, int N, int K, OffN off)
{
  const int z = blockIdx.z;
  const int m0 = blockIdx.y * 256, n0 = blockIdx.x * 256;
  if (MODE == MODE_SCORES && blockIdx.x > blockIdx.y) return;
  const unsigned short* A = Abase + off.a[z];
  const unsigned short* B = Bbase + off.b[z];
  const int kmax = (MODE == MODE_PV) ? (K < m0 + 256 ? K : m0 + 256) : K;
  const int nkt = kmax >> 6;

  __shared__ unsigned short As[2][2][8192];
  __shared__ unsigned short Bs[2][2][8192];

  const int tid = threadIdx.x;
  const int l = tid & 63;
  const int wid = tid >> 6;
  const int wm = wid >> 1;   // 0..3: 32-row slice within each quadrant
  const int wn = wid & 1;    // 0..1: 64-col slice within each quadrant

  // staging: thread covers 2 chunks of 1024B; row-in-half r, source col
  // pre-swizzled so the linear LDS write lands the involution layout.
  const int r0s = wid * 16 + (l >> 3);
  const int ces = ((l & 7) ^ (l >> 3)) << 3;   // source col in elements
  const size_t aR0 = (size_t)(m0 + r0s) * lda + ces;
  const size_t aR1 = aR0 + (size_t)8 * lda;
  const size_t bR0 = (size_t)(n0 + r0s) * ldb + ces;
  const size_t bR1 = bR0 + (size_t)8 * ldb;
  const size_t hA = (size_t)128 * lda, hB = (size_t)128 * ldb;
  const int dst0 = wid * 1024 + l * 8;   // ushort offset within 16KB half
  const int dst1 = dst0 + 512;

#define STAGE_A(bf, h, kkv) do {                                   \
    unsigned short* Lp = &As[bf][h][0];                            \
    load_lds16(A + aR0 + ((h) ? hA : 0) + (kkv), Lp + dst0);       \
    load_lds16(A + aR1 + ((h) ? hA : 0) + (kkv), Lp + dst1);       \
  } while (0)
#define STAGE_B(bf, h, kkv) do {                                   \
    unsigned short* Lp = &Bs[bf][h][0];                            \
    load_lds16(B + bR0 + ((h) ? hB : 0) + (kkv), Lp + dst0);       \
    load_lds16(B + bR1 + ((h) ? hB : 0) + (kkv), Lp + dst1);       \
  } while (0)

  f32x4 acc[2][2][2][4] = {};
  bf16x8 af[2][2], bfx[4][2];

  // prologue: tile0 all 4 halves, then tile1's {Ah0, Bh1}; wait tile0 only.
  STAGE_A(0, 0, 0); STAGE_B(0, 1, 0); STAGE_A(0, 1, 0); STAGE_B(0, 0, 0);
  if (nkt > 1) { STAGE_A(1, 0, 64); STAGE_B(1, 1, 64); VMCNT4(); }
  else { VMCNT0(); }
  BAR();

#define PHASE(QM, QN, RDA, RDB, STG, WT) do {                                 \
    if (RDA) {                                                                \
      const unsigned short* Ah = &As[cur][QM][0];                             \
      _Pragma("unroll") for (int fm = 0; fm < 2; fm++)                        \
        _Pragma("unroll") for (int ks = 0; ks < 2; ks++)                      \
          af[fm][ks] = rdfrag(Ah, wm * 32 + fm * 16 + (l & 15), ks, l);       \
    }                                                                         \
    if (RDB) {                                                                \
      const unsigned short* Bh = &Bs[cur][QN][0];                             \
      _Pragma("unroll") for (int fn = 0; fn < 4; fn++)                        \
        _Pragma("unroll") for (int ks = 0; ks < 2; ks++)                      \
          bfx[fn][ks] = rdfrag(Bh, wn * 64 + fn * 16 + (l & 15), ks, l);      \
    }                                                                         \
    STG;                                                                      \
    BAR();                                                                    \
    LGKM0();                                                                  \
    __builtin_amdgcn_s_setprio(1);                                            \
    _Pragma("unroll") for (int ks = 0; ks < 2; ks++)                          \
      _Pragma("unroll") for (int fm = 0; fm < 2; fm++)                        \
        _Pragma("unroll") for (int fn = 0; fn < 4; fn++)                      \
          acc[QM][QN][fm][fn] = __builtin_amdgcn_mfma_f32_16x16x32_bf16(      \
              af[fm][ks], bfx[fn][ks], acc[QM][QN][fm][fn], 0, 0, 0);         \
    __builtin_amdgcn_s_setprio(0);                                            \
    WT;                                                                       \
    BAR();                                                                    \
  } while (0)

  for (int t = 0; t < nkt; ++t) {
    const int cur = t & 1, nxt = cur ^ 1;
    const int kk1 = (t + 1) << 6, kk2 = (t + 2) << 6;
    const bool s1 = (t + 1 < nkt), s2 = (t + 2 < nkt);
    // phase order (0,0)->(0,1)->(1,1)->(1,0) enables frag reuse (A at P2/P4,
    // B at P3) and progressive half freeing: Ah0 free after P1, Bh1 after P2.
    PHASE(0, 0, 1, 1, { if (s1) STAGE_A(nxt, 1, kk1); }, {});
    PHASE(0, 1, 0, 1, { if (s1) STAGE_B(nxt, 0, kk1); }, {});
    PHASE(1, 1, 1, 0, { if (s2) STAGE_A(cur, 0, kk2); }, {});
    PHASE(1, 0, 0, 1, { if (s2) STAGE_B(cur, 1, kk2); },
          { if (s2) { VMCNT4(); } else { VMCNT0(); } });
  }
#undef PHASE
#undef STAGE_A
#undef STAGE_B

  const int r0c = (l >> 4) << 2;
#pragma unroll
  for (int Qn = 0; Qn < 2; Qn++)
#pragma unroll
    for (int fn = 0; fn < 4; fn++) {
      const int col = n0 + Qn * 128 + wn * 64 + fn * 16 + (l & 15);
      const float bv = bias ? bias[col] : 0.f;
#pragma unroll
      for (int Qm = 0; Qm < 2; Qm++)
#pragma unroll
        for (int fm = 0; fm < 2; fm++)
#pragma unroll
          for (int r = 0; r < 4; r++) {
            const int row = m0 + Qm * 128 + wm * 32 + fm * 16 + r0c + r;
            float v = acc[Qm][Qn][fm][fn][r] + bv;
            if (EPI == EPI_QKV) {
              const int sel = col >= 4608 ? 2 : (col >= 2304 ? 1 : 0);
              const size_t ci = (size_t)sel * (8192ull * 2304) +
                                (size_t)row * 2304 + (col - sel * 2304);
              ((unsigned short*)Cbase)[ci] = bf16bits(v);
            } else {
              const size_t ci = off.c[z] + (size_t)row * ldc + col;
              if (EPI == EPI_BF16)      ((unsigned short*)Cbase)[ci] = bf16bits(v);
              else if (EPI == EPI_F32)  ((float*)Cbase)[ci] = v;
              else                      ((float*)Cbase)[ci] = v > 0.f ? v : 0.01f * v;
            }
          }
    }
}

// ---------------- 128x128 simple GEMM (kept for skinny-N projections) --------
template<int EPI, int MODE>
__global__ __launch_bounds__(256) void k_gemm(
    const unsigned short* __restrict__ Abase, long lda,
    const unsigned short* __restrict__ Bbase, long ldb,
    const float* __restrict__ bias,
    void* __restrict__ Cbase, long ldc,
    int M, int N, int K, OffN off)
{
  const int z = blockIdx.z;
  const int m0 = blockIdx.y * 128, n0 = blockIdx.x * 128;
  if (MODE == MODE_SCORES && n0 > m0 + 127) return;
  const unsigned short* A = Abase + off.a[z];
  const unsigned short* B = Bbase + off.b[z];
  const int kmax = (MODE == MODE_PV) ? (K < m0 + 128 ? K : m0 + 128) : K;

  __shared__ unsigned short As[128 * 32];
  __shared__ unsigned short Bs[128 * 32];

  const int tid = threadIdx.x;
  const int l = tid & 63;
  const int wr = tid >> 7;
  const int wc = (tid >> 6) & 1;
  const int srow = tid >> 2;
  const int scol = (tid & 3) << 3;

  f32x4 acc[4][4] = {};

  const size_t aoff = (size_t)(m0 + srow) * lda + scol;
  const size_t boff = (size_t)(n0 + srow) * ldb + scol;

  for (int kk = 0; kk < kmax; kk += 32) {
    __syncthreads();
    load_lds16(A + aoff + kk,            &As[(size_t)tid * 8]);
    load_lds16(A + aoff + 64 * lda + kk, &As[2048 + (size_t)tid * 8]);
    load_lds16(B + boff + kk,            &Bs[(size_t)tid * 8]);
    load_lds16(B + boff + 64 * ldb + kk, &Bs[2048 + (size_t)tid * 8]);
    __syncthreads();

    const int kc = (l >> 4) << 3;
    const int rA = wr * 64 + (l & 15);
    const int rB = wc * 64 + (l & 15);
    bf16x8 af[4], bfr[4];
#pragma unroll
    for (int i = 0; i < 4; i++) {
      af[i]  = *(const bf16x8*)&As[(rA + i * 16) * 32 + kc];
      bfr[i] = *(const bf16x8*)&Bs[(rB + i * 16) * 32 + kc];
    }
#pragma unroll
    for (int mi = 0; mi < 4; mi++)
#pragma unroll
      for (int ni = 0; ni < 4; ni++)
        acc[mi][ni] = __builtin_amdgcn_mfma_f32_16x16x32_bf16(af[mi], bfr[ni], acc[mi][ni], 0, 0, 0);
  }

  const int r0 = m0 + wr * 64 + ((l >> 4) << 2);
  const int c0 = n0 + wc * 64 + (l & 15);
#pragma unroll
  for (int ni = 0; ni < 4; ni++) {
    const int col = c0 + ni * 16;
    const float bv = bias ? bias[col] : 0.f;
#pragma unroll
    for (int mi = 0; mi < 4; mi++) {
#pragma unroll
      for (int r = 0; r < 4; r++) {
        const int row = r0 + mi * 16 + r;
        float v = acc[mi][ni][r] + bv;
        const size_t ci = off.c[z] + (size_t)row * ldc + col;
        if (EPI == EPI_BF16)      ((unsigned short*)Cbase)[ci] = bf16bits(v);
        else if (EPI == EPI_F32)  ((float*)Cbase)[ci] = v;
        else                      ((float*)Cbase)[ci] = v > 0.f ? v : 0.01f * v;
      }
    }
  }
}

// ---------------- helpers ----------------
__global__ __launch_bounds__(256) void k_cast_x(const float* __restrict__ in,
                                                unsigned short* __restrict__ out) {
  const size_t i = ((size_t)blockIdx.x * 256 + threadIdx.x) * 4;
  float4 v = *(const float4*)&in[i];
  ushort4 o;
  o.x = bf16bits(v.x); o.y = bf16bits(v.y); o.z = bf16bits(v.z); o.w = bf16bits(v.w);
  *(ushort4*)&out[i] = o;
}

__global__ __launch_bounds__(256) void k_wt(const float* __restrict__ in,
                                            unsigned short* __restrict__ out,
                                            int R, int C) {
  __shared__ float tile[32][33];
  const int c0 = blockIdx.x * 32, r0 = blockIdx.y * 32;
  const int tx = threadIdx.x, ty = threadIdx.y;
#pragma unroll
  for (int k = 0; k < 4; k++)
    tile[ty + 8 * k][tx] = in[(size_t)(r0 + ty + 8 * k) * C + c0 + tx];
  __syncthreads();
#pragma unroll
  for (int k = 0; k < 4; k++)
    out[(size_t)(c0 + ty + 8 * k) * R + r0 + tx] = bf16bits(tile[tx][ty + 8 * k]);
}

__global__ __launch_bounds__(256) void k_bias_concat(const float* __restrict__ bq,
                                                     const float* __restrict__ bk,
                                                     const float* __restrict__ bv,
                                                     float* __restrict__ out) {
  const int i = blockIdx.x * 256 + threadIdx.x;
  if (i < 2304) out[i] = bq[i];
  else if (i < 4608) out[i] = bk[i - 2304];
  else if (i < 6912) out[i] = bv[i - 4608];
}

__global__ __launch_bounds__(256) void k_tv(const unsigned short* __restrict__ V,
                                            unsigned short* __restrict__ Vt) {
  const int bh = blockIdx.z, b = bh / 3, h = bh % 3;
  const int s0 = blockIdx.x * 64, d0 = blockIdx.y * 64;
  __shared__ unsigned short tile[64][65];
  const int t = threadIdx.x;
  const int tr = t >> 4, tc4 = (t & 15) << 2;
  const unsigned short* src = V + (size_t)(b * 2048 + s0) * 2304 + h * 768 + d0;
#pragma unroll
  for (int p = 0; p < 4; p++) {
    int sr = p * 16 + tr;
    ushort4 v = *(const ushort4*)&src[(size_t)sr * 2304 + tc4];
    tile[sr][tc4] = v.x; tile[sr][tc4 + 1] = v.y; tile[sr][tc4 + 2] = v.z; tile[sr][tc4 + 3] = v.w;
  }
  __syncthreads();
  unsigned short* dst = Vt + (size_t)(bh * 768 + d0) * 2048 + s0;
#pragma unroll
  for (int p = 0; p < 4; p++) {
    int dr = p * 16 + tr;
    ushort4 v;
    v.x = tile[tc4][dr]; v.y = tile[tc4 + 1][dr]; v.z = tile[tc4 + 2][dr]; v.w = tile[tc4 + 3][dr];
    *(ushort4*)&dst[(size_t)dr * 2048 + tc4] = v;
  }
}

// causal row softmax IN PLACE; zero-fill out to the 256-tile boundary so the
// 256-wide PV K-tiles never read unwritten bytes.
__global__ __launch_bounds__(256) void k_softmax(float* __restrict__ Sc) {
  const int i = blockIdx.x;
  const size_t zo = (size_t)blockIdx.y * 2048 * 2048;
  float* srow = Sc + zo + (size_t)i * 2048;
  unsigned short* prow = (unsigned short*)Sc + zo * 2 + (size_t)i * 4096;
  const int t = threadIdx.x;
  const int kb = ((i >> 8) + 1) << 8;
  float s[8];
  float mx = -1e30f;
#pragma unroll
  for (int j = 0; j < 8; j++) {
    const int col = j * 256 + t;
    s[j] = (((j << 8) < kb) && col <= i) ? srow[col] : -1e30f;
    mx = fmaxf(mx, s[j]);
  }
#pragma unroll
  for (int o = 32; o >= 1; o >>= 1) mx = fmaxf(mx, __shfl_xor(mx, o, 64));
  __shared__ float rmax[4], rsum[4];
  const int w = t >> 6;
  if ((t & 63) == 0) rmax[w] = mx;
  __syncthreads();
  mx = fmaxf(fmaxf(rmax[0], rmax[1]), fmaxf(rmax[2], rmax[3]));
  float sum = 0.f;
#pragma unroll
  for (int j = 0; j < 8; j++) {
    const int col = j * 256 + t;
    const float e = (((j << 8) < kb) && col <= i) ? expf(s[j] - mx) : 0.f;
    s[j] = e;
    sum += e;
  }
#pragma unroll
  for (int o = 32; o >= 1; o >>= 1) sum += __shfl_xor(sum, o, 64);
  if ((t & 63) == 0) rsum[w] = sum;
  __syncthreads();
  sum = rsum[0] + rsum[1] + rsum[2] + rsum[3];
  const float inv = 1.f / sum;
#pragma unroll
  for (int j = 0; j < 8; j++) {
    const int col = j * 256 + t;
    if (((j << 8) < kb) && col < kb) prow[col] = bf16bits(s[j] * inv);
  }
}

__global__ __launch_bounds__(256) void k_red1(const float* __restrict__ a,
                                              float* __restrict__ part) {
  float s = 0.f;
  for (size_t idx = (size_t)blockIdx.x * 256 + threadIdx.x; idx < 6291456ull; idx += 2048ull * 256)
    s += a[idx];
#pragma unroll
  for (int o = 32; o >= 1; o >>= 1) s += __shfl_xor(s, o, 64);
  __shared__ float r[4];
  const int t = threadIdx.x, w = t >> 6;
  if ((t & 63) == 0) r[w] = s;
  __syncthreads();
  if (t == 0) part[blockIdx.x] = r[0] + r[1] + r[2] + r[3];
}

__global__ __launch_bounds__(256) void k_red2(const float* __restrict__ part,
                                              float* __restrict__ mean) {
  const int t = threadIdx.x;
  float s = 0.f;
  for (int i = t; i < 2048; i += 256) s += part[i];
#pragma unroll
  for (int o = 32; o >= 1; o >>= 1) s += __shfl_xor(s, o, 64);
  __shared__ float r[4];
  const int w = t >> 6;
  if ((t & 63) == 0) r[w] = s;
  __syncthreads();
  if (t == 0) mean[0] = (r[0] + r[1] + r[2] + r[3]) * (1.f / 6291456.f);
}

__global__ __launch_bounds__(256) void k_residual(const float* __restrict__ a,
                                                  const float* __restrict__ x,
                                                  const float* __restrict__ meanp,
                                                  unsigned short* __restrict__ yb) {
  const float mean = meanp[0];
  const size_t i = ((size_t)blockIdx.x * 256 + threadIdx.x) * 4;
  float4 av = *(const float4*)&a[i];
  float4 xv = *(const float4*)&x[i];
  ushort4 o;
  o.x = bf16bits(av.x - mean + xv.x);
  o.y = bf16bits(av.y - mean + xv.y);
  o.z = bf16bits(av.z - mean + xv.z);
  o.w = bf16bits(av.w - mean + xv.w);
  *(ushort4*)&yb[i] = o;
}

extern "C" void kernel_launch(void* const* d_in, const int* in_sizes, int n_in,
                              void* d_out, int out_size, void* d_ws, size_t ws_size,
                              hipStream_t stream) {
  const float* x   = (const float*)d_in[0];
  const float* Wq  = (const float*)d_in[1];
  const float* bq  = (const float*)d_in[2];
  const float* Wk  = (const float*)d_in[3];
  const float* bk  = (const float*)d_in[4];
  const float* Wv  = (const float*)d_in[5];
  const float* bv  = (const float*)d_in[6];
  const float* Wo  = (const float*)d_in[7];
  const float* bo  = (const float*)d_in[8];
  const float* Wf  = (const float*)d_in[9];
  const float* bfb = (const float*)d_in[10];

  char* ws = (char*)d_ws;
  const size_t o_xb  = 0;
  const size_t o_Wqkvt = 12582912;
  const size_t o_Wot = o_Wqkvt + 10616832;
  const size_t o_Wft = o_Wot + 3538944;
  const size_t o_bqkv = o_Wft + 1179648;
  const size_t o_prt = o_bqkv + 32768;
  const size_t o_mn  = o_prt + 8192;
  const size_t o_Q   = o_mn + 128;
  const size_t MSZ   = 37748736;
  const size_t o_K   = o_Q + MSZ;
  const size_t o_V   = o_K + MSZ;
  const size_t o_Vt  = o_V + MSZ;
  const size_t o_O   = o_Vt + MSZ;
  const size_t o_end = o_O + MSZ;
  const size_t SC1   = 16777216;
  if (ws_size < o_end) return;

  size_t o_Sc; int hpc;
  {
    size_t avail = ws_size - o_end;
    hpc = (int)(avail / SC1); if (hpc > 12) hpc = 12;
    if (hpc >= 2) { o_Sc = o_end; }
    else { o_Sc = o_V; hpc = 2; }
  }

  const size_t o_a  = o_Q;
  const size_t o_yb = o_K;

  OffN z0{};
  dim3 b32(32, 8);

  k_cast_x<<<6144, 256, 0, stream>>>(x, (unsigned short*)(ws + o_xb));
  k_wt<<<dim3(72, 24), b32, 0, stream>>>(Wq, (unsigned short*)(ws + o_Wqkvt), 768, 2304);
  k_wt<<<dim3(72, 24), b32, 0, stream>>>(Wk, (unsigned short*)(ws + o_Wqkvt) + 2304 * 768, 768, 2304);
  k_wt<<<dim3(72, 24), b32, 0, stream>>>(Wv, (unsigned short*)(ws + o_Wqkvt) + 2 * 2304 * 768, 768, 2304);
  k_wt<<<dim3(24, 72), b32, 0, stream>>>(Wo, (unsigned short*)(ws + o_Wot), 2304, 768);
  k_wt<<<dim3(24, 24), b32, 0, stream>>>(Wf, (unsigned short*)(ws + o_Wft), 768, 768);
  k_bias_concat<<<27, 256, 0, stream>>>(bq, bk, bv, (float*)(ws + o_bqkv));

  // fused QKV: [8192,768] x [6912,768]^T -> demux into Q|K|V (256^2 kernel)
  k_gemm256<EPI_QKV, MODE_PLAIN><<<dim3(27, 32, 1), 512, 0, stream>>>(
      (const unsigned short*)(ws + o_xb), 768, (const unsigned short*)(ws + o_Wqkvt), 768,
      (const float*)(ws + o_bqkv), ws + o_Q, 2304, 8192, 6912, 768, z0);

  k_tv<<<dim3(32, 12, 12), 256, 0, stream>>>((const unsigned short*)(ws + o_V),
                                             (unsigned short*)(ws + o_Vt));

  for (int h0 = 0; h0 < 12; h0 += hpc) {
    const int cnt = (12 - h0) < hpc ? (12 - h0) : hpc;
    OffN so{}, po{};
    for (int zz = 0; zz < cnt; zz++) {
      const int bh = h0 + zz, b = bh / 3, h = bh % 3;
      so.a[zz] = (size_t)b * 2048 * 2304 + (size_t)h * 768;
      so.b[zz] = so.a[zz];
      so.c[zz] = (size_t)zz * 2048 * 2048;
      po.a[zz] = (size_t)zz * 2048 * 2048 * 2;
      po.b[zz] = (size_t)bh * 768 * 2048;
      po.c[zz] = (size_t)b * 2048 * 2304 + (size_t)h * 768;
    }
    k_gemm256<EPI_F32, MODE_SCORES><<<dim3(8, 8, cnt), 512, 0, stream>>>(
        (const unsigned short*)(ws + o_Q), 2304, (const unsigned short*)(ws + o_K), 2304, nullptr,
        ws + o_Sc, 2048, 2048, 2048, 768, so);
    k_softmax<<<dim3(2048, cnt), 256, 0, stream>>>((float*)(ws + o_Sc));
    k_gemm256<EPI_BF16, MODE_PV><<<dim3(3, 8, cnt), 512, 0, stream>>>(
        (const unsigned short*)(ws + o_Sc), 4096, (const unsigned short*)(ws + o_Vt), 2048, nullptr,
        ws + o_O, 2304, 2048, 768, 2048, po);
  }

  k_gemm<EPI_F32, MODE_PLAIN><<<dim3(6, 64, 1), 256, 0, stream>>>(
      (const unsigned short*)(ws + o_O), 2304, (const unsigned short*)(ws + o_Wot), 2304, bo,
      ws + o_a, 768, 8192, 768, 2304, z0);

  k_red1<<<2048, 256, 0, stream>>>((const float*)(ws + o_a), (float*)(ws + o_prt));
  k_red2<<<1, 256, 0, stream>>>((const float*)(ws + o_prt), (float*)(ws + o_mn));
  k_residual<<<6144, 256, 0, stream>>>((const float*)(ws + o_a), x,
                                       (const float*)(ws + o_mn), (unsigned short*)(ws + o_yb));

  k_gemm<EPI_LEAKY, MODE_PLAIN><<<dim3(6, 64, 1), 256, 0, stream>>>(
      (const unsigned short*)(ws + o_yb), 768, (const unsigned short*)(ws + o_Wft), 768, bfb,
      d_out, 768, 8192, 768, 768, z0);
}

// Round 4
// 589.182 us; speedup vs baseline: 1.1882x; 1.1882x over previous
//
#include <hip/hip_runtime.h>
#include <hip/hip_bf16.h>

typedef __attribute__((ext_vector_type(8))) __bf16 bf16x8;
typedef __attribute__((ext_vector_type(4))) float f32x4;
typedef unsigned short u16;

#define DEV static __device__ __forceinline__

#define BAR() asm volatile("s_barrier" ::: "memory")
#define LGKM0() asm volatile("s_waitcnt lgkmcnt(0)" ::: "memory")
#define VMCNT4() asm volatile("s_waitcnt vmcnt(4)" ::: "memory")
#define VMCNT0() asm volatile("s_waitcnt vmcnt(0)" ::: "memory")

DEV void load_lds16(const void* g, void* l) {
  __builtin_amdgcn_global_load_lds(
      (const __attribute__((address_space(1))) unsigned int*)g,
      (__attribute__((address_space(3))) unsigned int*)l, 16, 0, 0);
}

DEV u16 bf16bits(float v) {
  __hip_bfloat16 h = __float2bfloat16(v);
  return __builtin_bit_cast(u16, h);
}

// swizzled LDS frag read (half = 128x64 bf16, XOR involution on 16B chunks)
DEV bf16x8 rdfrag(const u16* half, int row, int ks, int l) {
  const int cb = (((ks << 6) | ((l >> 4) << 4)) ^ ((l & 7) << 4));
  return *(const bf16x8*)((const char*)half + row * 128 + cb);
}

struct OffN { unsigned long long a[12], b[12], c[12]; };

enum { EPI_BF16 = 0, EPI_F32 = 1, EPI_LEAKY = 2 };
enum { MODE_PLAIN = 0, MODE_SCP = 1, MODE_PVP = 2 };  // SCP/PVP: causal-packed S

// ---------------- QKV 256x256 deep-pipelined GEMM (8 waves, BK=64) -----------
// Fixed shape: [8192,768] x [6912,768]^T + bias -> demux bf16 into Q|K|V.
// B quadrant frags fully register-cached (24 ds_read_b128 / K-tile / wave).
// LDS C-tile epilogue -> coalesced 16B stores.
__global__ __launch_bounds__(512, 1) void k_qkv256(
    const u16* __restrict__ A, const u16* __restrict__ B,
    const float* __restrict__ bias, u16* __restrict__ C)
{
  // grid (27,32): bijective XCD swizzle, 864 = 8 * 108
  int flat = blockIdx.y * 27 + blockIdx.x;
  flat = (flat & 7) * 108 + (flat >> 3);
  const int n0 = (flat % 27) * 256, m0 = (flat / 27) * 256;
  const int lda = 768, ldb = 768, nkt = 12;

  __shared__ u16 smem[65536];           // 128KB: As|Bs during loop, C-tile after
  u16* As0 = smem;                      // [2][2][8192]
  u16* Bs0 = smem + 32768;

  const int tid = threadIdx.x;
  const int l = tid & 63;
  const int wid = tid >> 6;
  const int wm = wid >> 1, wn = wid & 1;

  const int r0s = wid * 16 + (l >> 3);
  const int ces = ((l & 7) ^ (l >> 3)) << 3;   // pre-swizzled source col
  const size_t aR0 = (size_t)(m0 + r0s) * lda + ces;
  const size_t aR1 = aR0 + (size_t)8 * lda;
  const size_t bR0 = (size_t)(n0 + r0s) * ldb + ces;
  const size_t bR1 = bR0 + (size_t)8 * ldb;
  const size_t hA = (size_t)128 * lda, hB = (size_t)128 * ldb;
  const int dst0 = wid * 1024 + l * 8, dst1 = dst0 + 512;

#define STAGE_A(bf, h, kkv) do {                                 \
    u16* Lp = As0 + (bf) * 16384 + (h) * 8192;                   \
    load_lds16(A + aR0 + ((h) ? hA : 0) + (kkv), Lp + dst0);     \
    load_lds16(A + aR1 + ((h) ? hA : 0) + (kkv), Lp + dst1);     \
  } while (0)
#define STAGE_B(bf, h, kkv) do {                                 \
    u16* Lp = Bs0 + (bf) * 16384 + (h) * 8192;                   \
    load_lds16(B + bR0 + ((h) ? hB : 0) + (kkv), Lp + dst0);     \
    load_lds16(B + bR1 + ((h) ? hB : 0) + (kkv), Lp + dst1);     \
  } while (0)

  f32x4 acc[2][2][2][4] = {};
  bf16x8 af[2][2], bA[4][2], bB[4][2];

  STAGE_A(0, 0, 0); STAGE_B(0, 1, 0); STAGE_A(0, 1, 0); STAGE_B(0, 0, 0);
  STAGE_A(1, 0, 64); STAGE_B(1, 1, 64);
  VMCNT4();
  BAR();

#define MFMA16(QM, QN, BARR)                                                  \
    __builtin_amdgcn_s_setprio(1);                                            \
    _Pragma("unroll") for (int ks = 0; ks < 2; ks++)                          \
      _Pragma("unroll") for (int fm = 0; fm < 2; fm++)                        \
        _Pragma("unroll") for (int fn = 0; fn < 4; fn++)                      \
          acc[QM][QN][fm][fn] = __builtin_amdgcn_mfma_f32_16x16x32_bf16(      \
              af[fm][ks], BARR[fn][ks], acc[QM][QN][fm][fn], 0, 0, 0);        \
    __builtin_amdgcn_s_setprio(0);

#define RD_A(half)                                                            \
    _Pragma("unroll") for (int fm = 0; fm < 2; fm++)                          \
      _Pragma("unroll") for (int ks = 0; ks < 2; ks++)                        \
        af[fm][ks] = rdfrag(half, wm * 32 + fm * 16 + (l & 15), ks, l);
#define RD_B(dstv, half)                                                      \
    _Pragma("unroll") for (int fn = 0; fn < 4; fn++)                          \
      _Pragma("unroll") for (int ks = 0; ks < 2; ks++)                        \
        dstv[fn][ks] = rdfrag(half, wn * 64 + fn * 16 + (l & 15), ks, l);

  for (int t = 0; t < nkt; ++t) {
    const int cur = t & 1, nxt = cur ^ 1;
    const int kk1 = (t + 1) << 6, kk2 = (t + 2) << 6;
    const bool s1 = (t + 1 < nkt), s2 = (t + 2 < nkt);
    // P1: quadrant (0,0)
    RD_A(As0 + cur * 16384);
    RD_B(bA, Bs0 + cur * 16384);
    if (s1) STAGE_A(nxt, 1, kk1);
    BAR(); LGKM0();
    MFMA16(0, 0, bA);
    BAR();
    // P2: (0,1)
    RD_B(bB, Bs0 + cur * 16384 + 8192);
    if (s1) STAGE_B(nxt, 0, kk1);
    BAR(); LGKM0();
    MFMA16(0, 1, bB);
    BAR();
    // P3: (1,1)
    RD_A(As0 + cur * 16384 + 8192);
    if (s2) STAGE_A(cur, 0, kk2);
    BAR(); LGKM0();
    MFMA16(1, 1, bB);
    BAR();
    // P4: (1,0) - no LDS reads (bA cached)
    if (s2) STAGE_B(cur, 1, kk2);
    BAR(); LGKM0();
    MFMA16(1, 0, bA);
    if (s2) { VMCNT4(); } else { VMCNT0(); }
    BAR();
  }
#undef RD_A
#undef RD_B
#undef MFMA16
#undef STAGE_A
#undef STAGE_B

  // ---- LDS-staged coalesced epilogue with demux (sel uniform: 2304 = 9*256)
  __syncthreads();
  const int sel = n0 >= 4608 ? 2 : (n0 >= 2304 ? 1 : 0);
  const int r0c = (l >> 4) << 2;
#pragma unroll
  for (int Qm = 0; Qm < 2; Qm++)
#pragma unroll
    for (int Qn = 0; Qn < 2; Qn++)
#pragma unroll
      for (int fn = 0; fn < 4; fn++) {
        const int coll = Qn * 128 + wn * 64 + fn * 16 + (l & 15);
        const float bv = bias[n0 + coll];
#pragma unroll
        for (int fm = 0; fm < 2; fm++)
#pragma unroll
          for (int r = 0; r < 4; r++) {
            const int rowl = Qm * 128 + wm * 32 + fm * 16 + r0c + r;
            smem[rowl * 256 + (coll ^ (((rowl >> 2) & 3) << 4))] =
                bf16bits(acc[Qm][Qn][fm][fn][r] + bv);
          }
      }
  __syncthreads();
  u16* Cb = C + (size_t)sel * (8192ull * 2304) + (n0 - sel * 2304);
#pragma unroll
  for (int j = 0; j < 16; j++) {
    const int rowl = j * 16 + (tid >> 5);
    const int c = (tid & 31) * 8;
    bf16x8 v = *(const bf16x8*)&smem[rowl * 256 + (c ^ (((rowl >> 2) & 3) << 4))];
    *(bf16x8*)&Cb[(size_t)(m0 + rowl) * 2304 + c] = v;
  }
}

// ---------------- 128x128 GEMM (4 waves, BK=32) -------------------------------
// MODE_SCP: causal-packed f32 S output + triangle grid.
// MODE_PVP: reads causal-packed bf16 P (overlay) as A.
// EPI_BF16: LDS-staged coalesced bf16 epilogue.
template<int EPI, int MODE>
__global__ __launch_bounds__(256) void k_gemm(
    const u16* __restrict__ Abase, long lda,
    const u16* __restrict__ Bbase, long ldb,
    const float* __restrict__ bias,
    void* __restrict__ Cbase, long ldc,
    int M, int N, int K, OffN off)
{
  const int z = blockIdx.z;
  const int m0 = blockIdx.y * 128, n0 = blockIdx.x * 128;
  const int rb = m0 >> 8;
  if (MODE == MODE_SCP && blockIdx.x > 2 * (blockIdx.y >> 1) + 1) return;

  const u16* A = Abase + off.a[z];
  const u16* B = Bbase + off.b[z];
  int kmax = K;
  int mrow0 = m0;
  if (MODE == MODE_PVP) {
    kmax = (rb + 1) << 8;                       // packed causal span
    lda = (long)kmax * 2;                       // u16 pitch of P overlay rows
    A += (size_t)65536 * rb * (rb + 1);         // packed row-block base (u16)
    mrow0 = m0 & 255;
  }

  __shared__ u16 smem[16384];                   // 32KB: As|Bs, C-tile after
  u16* As = smem;
  u16* Bs = smem + 4096;

  const int tid = threadIdx.x;
  const int l = tid & 63;
  const int wr = tid >> 7;
  const int wc = (tid >> 6) & 1;
  const int srow = tid >> 2;
  const int scol = (tid & 3) << 3;

  f32x4 acc[4][4] = {};

  const size_t aoff = (size_t)(mrow0 + srow) * lda + scol;
  const size_t boff = (size_t)(n0 + srow) * ldb + scol;

  for (int kk = 0; kk < kmax; kk += 32) {
    __syncthreads();
    load_lds16(A + aoff + kk,            As + (size_t)tid * 8);
    load_lds16(A + aoff + 64 * lda + kk, As + 2048 + (size_t)tid * 8);
    load_lds16(B + boff + kk,            Bs + (size_t)tid * 8);
    load_lds16(B + boff + 64 * ldb + kk, Bs + 2048 + (size_t)tid * 8);
    __syncthreads();

    const int kc = (l >> 4) << 3;
    const int rA = wr * 64 + (l & 15);
    const int rB = wc * 64 + (l & 15);
    bf16x8 af[4], bfr[4];
#pragma unroll
    for (int i = 0; i < 4; i++) {
      af[i]  = *(const bf16x8*)&As[(rA + i * 16) * 32 + kc];
      bfr[i] = *(const bf16x8*)&Bs[(rB + i * 16) * 32 + kc];
    }
#pragma unroll
    for (int mi = 0; mi < 4; mi++)
#pragma unroll
      for (int ni = 0; ni < 4; ni++)
        acc[mi][ni] = __builtin_amdgcn_mfma_f32_16x16x32_bf16(af[mi], bfr[ni], acc[mi][ni], 0, 0, 0);
  }

  if (EPI == EPI_BF16) {
    // LDS-staged coalesced bf16 epilogue
    __syncthreads();
#pragma unroll
    for (int ni = 0; ni < 4; ni++) {
      const int coll = wc * 64 + ni * 16 + (l & 15);
      const float bv = bias ? bias[n0 + coll] : 0.f;
#pragma unroll
      for (int mi = 0; mi < 4; mi++)
#pragma unroll
        for (int r = 0; r < 4; r++) {
          const int rowl = wr * 64 + mi * 16 + ((l >> 4) << 2) + r;
          smem[rowl * 128 + (coll ^ (((rowl >> 2) & 3) << 4))] =
              bf16bits(acc[mi][ni][r] + bv);
        }
    }
    __syncthreads();
    u16* Cb = (u16*)Cbase + off.c[z] + n0;
#pragma unroll
    for (int j = 0; j < 8; j++) {
      const int rowl = j * 16 + (tid >> 4);
      const int c = (tid & 15) * 8;
      bf16x8 v = *(const bf16x8*)&smem[rowl * 128 + (c ^ (((rowl >> 2) & 3) << 4))];
      *(bf16x8*)&Cb[(size_t)(m0 + rowl) * ldc + c] = v;
    }
  } else {
    const int r0 = wr * 64 + ((l >> 4) << 2);
    const int c0 = wc * 64 + (l & 15);
    const int ldcb = (rb + 1) << 8;
    const size_t pbase = off.c[z] + (size_t)32768 * rb * (rb + 1);
#pragma unroll
    for (int ni = 0; ni < 4; ni++) {
      const int col = n0 + c0 + ni * 16;
      const float bv = bias ? bias[col] : 0.f;
#pragma unroll
      for (int mi = 0; mi < 4; mi++) {
#pragma unroll
        for (int r = 0; r < 4; r++) {
          const int rowl = r0 + mi * 16 + r;
          float v = acc[mi][ni][r] + bv;
          size_t ci;
          if (MODE == MODE_SCP)
            ci = pbase + (size_t)((m0 & 255) + rowl) * ldcb + col;
          else
            ci = off.c[z] + (size_t)(m0 + rowl) * ldc + col;
          if (EPI == EPI_F32) ((float*)Cbase)[ci] = v;
          else                ((float*)Cbase)[ci] = v > 0.f ? v : 0.01f * v;
        }
      }
    }
  }
}

// ---------------- helpers ----------------
__global__ __launch_bounds__(256) void k_cast_x(const float* __restrict__ in,
                                                u16* __restrict__ out) {
  const size_t i = ((size_t)blockIdx.x * 256 + threadIdx.x) * 4;
  float4 v = *(const float4*)&in[i];
  ushort4 o;
  o.x = bf16bits(v.x); o.y = bf16bits(v.y); o.z = bf16bits(v.z); o.w = bf16bits(v.w);
  *(ushort4*)&out[i] = o;
}

__global__ __launch_bounds__(256) void k_wt(const float* __restrict__ in,
                                            u16* __restrict__ out, int R, int C) {
  __shared__ float tile[32][33];
  const int c0 = blockIdx.x * 32, r0 = blockIdx.y * 32;
  const int tx = threadIdx.x, ty = threadIdx.y;
#pragma unroll
  for (int k = 0; k < 4; k++)
    tile[ty + 8 * k][tx] = in[(size_t)(r0 + ty + 8 * k) * C + c0 + tx];
  __syncthreads();
#pragma unroll
  for (int k = 0; k < 4; k++)
    out[(size_t)(c0 + ty + 8 * k) * R + r0 + tx] = bf16bits(tile[tx][ty + 8 * k]);
}

__global__ __launch_bounds__(256) void k_bias_concat(const float* __restrict__ bq,
                                                     const float* __restrict__ bk,
                                                     const float* __restrict__ bv,
                                                     float* __restrict__ out) {
  const int i = blockIdx.x * 256 + threadIdx.x;
  if (i < 2304) out[i] = bq[i];
  else if (i < 4608) out[i] = bk[i - 2304];
  else if (i < 6912) out[i] = bv[i - 4608];
}

__global__ __launch_bounds__(256) void k_tv(const u16* __restrict__ V,
                                            u16* __restrict__ Vt) {
  const int bh = blockIdx.z, b = bh / 3, h = bh % 3;
  const int s0 = blockIdx.x * 64, d0 = blockIdx.y * 64;
  __shared__ u16 tile[64][65];
  const int t = threadIdx.x;
  const int tr = t >> 4, tc4 = (t & 15) << 2;
  const u16* src = V + (size_t)(b * 2048 + s0) * 2304 + h * 768 + d0;
#pragma unroll
  for (int p = 0; p < 4; p++) {
    int sr = p * 16 + tr;
    ushort4 v = *(const ushort4*)&src[(size_t)sr * 2304 + tc4];
    tile[sr][tc4] = v.x; tile[sr][tc4 + 1] = v.y; tile[sr][tc4 + 2] = v.z; tile[sr][tc4 + 3] = v.w;
  }
  __syncthreads();
  u16* dst = Vt + (size_t)(bh * 768 + d0) * 2048 + s0;
#pragma unroll
  for (int p = 0; p < 4; p++) {
    int dr = p * 16 + tr;
    ushort4 v;
    v.x = tile[tc4][dr]; v.y = tile[tc4 + 1][dr]; v.z = tile[tc4 + 2][dr]; v.w = tile[tc4 + 3][dr];
    *(ushort4*)&dst[(size_t)dr * 2048 + tc4] = v;
  }
}

// causal row softmax over PACKED S (in place): row i has (rb+1)*256 dense cols
__global__ __launch_bounds__(256) void k_softmax(float* __restrict__ Sc) {
  const int i = blockIdx.x;
  const int rb = i >> 8;
  const int nj = rb + 1;
  const int ldcb = nj << 8;
  const size_t base = (size_t)blockIdx.y * 2359296ull +
                      (size_t)32768 * rb * (rb + 1) + (size_t)(i & 255) * ldcb;
  float* srow = Sc + base;
  u16* prow = (u16*)Sc + base * 2;
  const int t = threadIdx.x;
  float s[8];
  float mx = -1e30f;
#pragma unroll
  for (int j = 0; j < 8; j++) {
    const int col = j * 256 + t;
    float v = -1e30f;
    if (j < nj && col <= i) v = srow[col];
    s[j] = v;
    mx = fmaxf(mx, v);
  }
#pragma unroll
  for (int o = 32; o >= 1; o >>= 1) mx = fmaxf(mx, __shfl_xor(mx, o, 64));
  __shared__ float rmax[4], rsum[4];
  const int w = t >> 6;
  if ((t & 63) == 0) rmax[w] = mx;
  __syncthreads();   // orders all srow reads before P writes below
  mx = fmaxf(fmaxf(rmax[0], rmax[1]), fmaxf(rmax[2], rmax[3]));
  float sum = 0.f;
#pragma unroll
  for (int j = 0; j < 8; j++) {
    const float e = (s[j] > -1e29f) ? expf(s[j] - mx) : 0.f;
    s[j] = e;
    sum += e;
  }
#pragma unroll
  for (int o = 32; o >= 1; o >>= 1) sum += __shfl_xor(sum, o, 64);
  if ((t & 63) == 0) rsum[w] = sum;
  __syncthreads();
  sum = rsum[0] + rsum[1] + rsum[2] + rsum[3];
  const float inv = 1.f / sum;
#pragma unroll
  for (int j = 0; j < 8; j++) {
    const int col = j * 256 + t;
    if (j < nj) prow[col] = bf16bits(s[j] * inv);
  }
}

__global__ __launch_bounds__(256) void k_red1(const float* __restrict__ a,
                                              float* __restrict__ part) {
  float s = 0.f;
  for (size_t idx = (size_t)blockIdx.x * 256 + threadIdx.x; idx < 6291456ull; idx += 2048ull * 256)
    s += a[idx];
#pragma unroll
  for (int o = 32; o >= 1; o >>= 1) s += __shfl_xor(s, o, 64);
  __shared__ float r[4];
  const int t = threadIdx.x, w = t >> 6;
  if ((t & 63) == 0) r[w] = s;
  __syncthreads();
  if (t == 0) part[blockIdx.x] = r[0] + r[1] + r[2] + r[3];
}

__global__ __launch_bounds__(256) void k_red2(const float* __restrict__ part,
                                              float* __restrict__ mean) {
  const int t = threadIdx.x;
  float s = 0.f;
  for (int i = t; i < 2048; i += 256) s += part[i];
#pragma unroll
  for (int o = 32; o >= 1; o >>= 1) s += __shfl_xor(s, o, 64);
  __shared__ float r[4];
  const int w = t >> 6;
  if ((t & 63) == 0) r[w] = s;
  __syncthreads();
  if (t == 0) mean[0] = (r[0] + r[1] + r[2] + r[3]) * (1.f / 6291456.f);
}

__global__ __launch_bounds__(256) void k_residual(const float* __restrict__ a,
                                                  const float* __restrict__ x,
                                                  const float* __restrict__ meanp,
                                                  u16* __restrict__ yb) {
  const float mean = meanp[0];
  const size_t i = ((size_t)blockIdx.x * 256 + threadIdx.x) * 4;
  float4 av = *(const float4*)&a[i];
  float4 xv = *(const float4*)&x[i];
  ushort4 o;
  o.x = bf16bits(av.x - mean + xv.x);
  o.y = bf16bits(av.y - mean + xv.y);
  o.z = bf16bits(av.z - mean + xv.z);
  o.w = bf16bits(av.w - mean + xv.w);
  *(ushort4*)&yb[i] = o;
}

extern "C" void kernel_launch(void* const* d_in, const int* in_sizes, int n_in,
                              void* d_out, int out_size, void* d_ws, size_t ws_size,
                              hipStream_t stream) {
  const float* x   = (const float*)d_in[0];
  const float* Wq  = (const float*)d_in[1];
  const float* bq  = (const float*)d_in[2];
  const float* Wk  = (const float*)d_in[3];
  const float* bk  = (const float*)d_in[4];
  const float* Wv  = (const float*)d_in[5];
  const float* bv  = (const float*)d_in[6];
  const float* Wo  = (const float*)d_in[7];
  const float* bo  = (const float*)d_in[8];
  const float* Wf  = (const float*)d_in[9];
  const float* bfb = (const float*)d_in[10];

  char* ws = (char*)d_ws;
  const size_t o_xb  = 0;
  const size_t o_Wqkvt = 12582912;
  const size_t o_Wot = o_Wqkvt + 10616832;
  const size_t o_Wft = o_Wot + 3538944;
  const size_t o_bqkv = o_Wft + 1179648;
  const size_t o_prt = o_bqkv + 32768;
  const size_t o_mn  = o_prt + 8192;
  const size_t o_Q   = o_mn + 128;
  const size_t MSZ   = 37748736;
  const size_t o_K   = o_Q + MSZ;
  const size_t o_V   = o_K + MSZ;
  const size_t o_Vt  = o_V + MSZ;
  const size_t o_O   = o_Vt + MSZ;
  const size_t o_end = o_O + MSZ;
  const size_t S1    = 9437184;      // packed causal S per head (f32)
  if (ws_size < o_end) return;

  size_t o_Sc; int hpc;
  if (ws_size - o_end >= 12 * S1) { o_Sc = o_end; hpc = 12; }
  else                            { o_Sc = o_V;  hpc = 4; }  // 4*S1 == MSZ (V dead)

  const size_t o_a  = o_Q;
  const size_t o_yb = o_K;

  OffN z0{};
  dim3 b32(32, 8);

  k_cast_x<<<6144, 256, 0, stream>>>(x, (u16*)(ws + o_xb));
  k_wt<<<dim3(72, 24), b32, 0, stream>>>(Wq, (u16*)(ws + o_Wqkvt), 768, 2304);
  k_wt<<<dim3(72, 24), b32, 0, stream>>>(Wk, (u16*)(ws + o_Wqkvt) + 2304 * 768, 768, 2304);
  k_wt<<<dim3(72, 24), b32, 0, stream>>>(Wv, (u16*)(ws + o_Wqkvt) + 2 * 2304 * 768, 768, 2304);
  k_wt<<<dim3(24, 72), b32, 0, stream>>>(Wo, (u16*)(ws + o_Wot), 2304, 768);
  k_wt<<<dim3(24, 24), b32, 0, stream>>>(Wf, (u16*)(ws + o_Wft), 768, 768);
  k_bias_concat<<<27, 256, 0, stream>>>(bq, bk, bv, (float*)(ws + o_bqkv));

  k_qkv256<<<dim3(27, 32), 512, 0, stream>>>(
      (const u16*)(ws + o_xb), (const u16*)(ws + o_Wqkvt),
      (const float*)(ws + o_bqkv), (u16*)(ws + o_Q));

  k_tv<<<dim3(32, 12, 12), 256, 0, stream>>>((const u16*)(ws + o_V), (u16*)(ws + o_Vt));

  for (int h0 = 0; h0 < 12; h0 += hpc) {
    const int cnt = (12 - h0) < hpc ? (12 - h0) : hpc;
    OffN so{}, po{};
    for (int zz = 0; zz < cnt; zz++) {
      const int bh = h0 + zz, b = bh / 3, h = bh % 3;
      so.a[zz] = (size_t)b * 2048 * 2304 + (size_t)h * 768;
      so.b[zz] = so.a[zz];
      so.c[zz] = (size_t)zz * 2359296;           // packed f32 elems
      po.a[zz] = (size_t)zz * 4718592;           // packed u16 elems (P overlay)
      po.b[zz] = (size_t)bh * 768 * 2048;
      po.c[zz] = (size_t)b * 2048 * 2304 + (size_t)h * 768;
    }
    k_gemm<EPI_F32, MODE_SCP><<<dim3(16, 16, cnt), 256, 0, stream>>>(
        (const u16*)(ws + o_Q), 2304, (const u16*)(ws + o_K), 2304, nullptr,
        ws + o_Sc, 0, 2048, 2048, 768, so);
    k_softmax<<<dim3(2048, cnt), 256, 0, stream>>>((float*)(ws + o_Sc));
    k_gemm<EPI_BF16, MODE_PVP><<<dim3(6, 16, cnt), 256, 0, stream>>>(
        (const u16*)(ws + o_Sc), 0, (const u16*)(ws + o_Vt), 2048, nullptr,
        ws + o_O, 2304, 2048, 768, 0, po);
  }

  k_gemm<EPI_F32, MODE_PLAIN><<<dim3(6, 64, 1), 256, 0, stream>>>(
      (const u16*)(ws + o_O), 2304, (const u16*)(ws + o_Wot), 2304, bo,
      ws + o_a, 768, 8192, 768, 2304, z0);

  k_red1<<<2048, 256, 0, stream>>>((const float*)(ws + o_a), (float*)(ws + o_prt));
  k_red2<<<1, 256, 0, stream>>>((const float*)(ws + o_prt), (float*)(ws + o_mn));
  k_residual<<<6144, 256, 0, stream>>>((const float*)(ws + o_a), x,
                                       (const float*)(ws + o_mn), (u16*)(ws + o_yb));

  k_gemm<EPI_LEAKY, MODE_PLAIN><<<dim3(6, 64, 1), 256, 0, stream>>>(
      (const u16*)(ws + o_yb), 768, (const u16*)(ws + o_Wft), 768, bfb,
      d_out, 768, 8192, 768, 768, z0);
}

// Round 5
// 550.429 us; speedup vs baseline: 1.2719x; 1.0704x over previous
//
#include <hip/hip_runtime.h>
#include <hip/hip_bf16.h>

typedef __attribute__((ext_vector_type(8))) __bf16 bf16x8;
typedef __attribute__((ext_vector_type(4))) float f32x4;
typedef unsigned short u16;

#define DEV static __device__ __forceinline__

#define BAR() asm volatile("s_barrier" ::: "memory")
#define LGKM0() asm volatile("s_waitcnt lgkmcnt(0)" ::: "memory")
#define VMCNT3() asm volatile("s_waitcnt vmcnt(3)" ::: "memory")
#define VMCNT0() asm volatile("s_waitcnt vmcnt(0)" ::: "memory")

DEV void load_lds16(const void* g, void* l) {
  __builtin_amdgcn_global_load_lds(
      (const __attribute__((address_space(1))) unsigned int*)g,
      (__attribute__((address_space(3))) unsigned int*)l, 16, 0, 0);
}

DEV u16 bf16bits(float v) {
  __hip_bfloat16 h = __float2bfloat16(v);
  return __builtin_bit_cast(u16, h);
}

// swizzled LDS frag read (half = 128x64 bf16, XOR involution on 16B chunks)
DEV bf16x8 rdfrag(const u16* half, int row, int ks, int l) {
  const int cb = (((ks << 6) | ((l >> 4) << 4)) ^ ((l & 7) << 4));
  return *(const bf16x8*)((const char*)half + row * 128 + cb);
}

struct OffN { unsigned long long a[12], b[12], c[12]; };

enum { G_QKV = 0, G_SC = 1, G_PV = 2 };
enum { EPI_F32 = 0, EPI_LEAKY = 1 };

// ---------------- unified 256x256 deep-pipelined GEMM (8 waves, BK=64) -------
// Stage schedule (race-free, issue order == need order per tile τ:
// Ah0,Bh0,Bh1,Ah1): P1(τ-1) stages A(τ)h1; P2..P4(τ-2) stage A(τ)h0,B(τ)h0,
// B(τ)h1. End-of-tile wait = vmcnt(3) (3 newest = t+2's partial group).
// G_QKV: fixed 8192x6912x768 + bias, demux bf16 -> Q|K|V.
// G_SC : scores, triangle grid, packed-causal f32 S out.
// G_PV : A = packed bf16 P overlay (variable K), B = Vt, bf16 O out.
template<int MODE>
__global__ __launch_bounds__(512, 1) void k_g256(
    const u16* __restrict__ Abase, const u16* __restrict__ Bbase,
    const float* __restrict__ bias, void* __restrict__ Cbase, OffN off)
{
  const int z = blockIdx.z;
  int m0, n0, nkt, rb;
  long lda, ldb;
  const u16 *A, *B;
  if (MODE == G_QKV) {
    int flat = blockIdx.y * 27 + blockIdx.x;       // 864 = 8 * 108, bijective
    flat = (flat & 7) * 108 + (flat >> 3);
    n0 = (flat % 27) * 256; m0 = (flat / 27) * 256;
    lda = 768; ldb = 768; nkt = 12; rb = 0;
    A = Abase; B = Bbase;
  } else if (MODE == G_SC) {
    if (blockIdx.x > blockIdx.y) return;           // causal triangle
    rb = blockIdx.y;
    m0 = rb * 256; n0 = blockIdx.x * 256;
    lda = 2304; ldb = 2304; nkt = 12;
    A = Abase + off.a[z]; B = Bbase + off.b[z];
  } else {
    rb = 7 - (int)blockIdx.y;                      // heavy row-blocks first
    m0 = rb * 256; n0 = blockIdx.x * 256;
    lda = (long)(rb + 1) * 512;                    // u16 pitch of P overlay
    ldb = 2048;
    nkt = (rb + 1) * 4;                            // K = (rb+1)*256
    A = Abase + off.a[z] + (size_t)65536 * rb * (rb + 1);
    B = Bbase + off.b[z];
  }
  const int arow0 = (MODE == G_PV) ? 0 : m0;

  __shared__ u16 smem[65536];            // As[2][2][8192] | Bs[2][2][8192]
  u16* As0 = smem;
  u16* Bs0 = smem + 32768;

  const int tid = threadIdx.x;
  const int l = tid & 63;
  const int wid = tid >> 6;
  const int wm = wid >> 1, wn = wid & 1;

  const int r0s = wid * 16 + (l >> 3);
  const int ces = ((l & 7) ^ (l >> 3)) << 3;       // pre-swizzled source col
  const size_t aR0 = (size_t)(arow0 + r0s) * lda + ces;
  const size_t aR1 = aR0 + (size_t)8 * lda;
  const size_t bR0 = (size_t)(n0 + r0s) * ldb + ces;
  const size_t bR1 = bR0 + (size_t)8 * ldb;
  const size_t hA = (size_t)128 * lda, hB = (size_t)128 * ldb;
  const int dst0 = wid * 1024 + l * 8, dst1 = dst0 + 512;

#define STAGE_A(bf, h, kkv) do {                                 \
    u16* Lp = As0 + (bf) * 16384 + (h) * 8192;                   \
    load_lds16(A + aR0 + ((h) ? hA : 0) + (kkv), Lp + dst0);     \
    load_lds16(A + aR1 + ((h) ? hA : 0) + (kkv), Lp + dst1);     \
  } while (0)
#define STAGE_B(bf, h, kkv) do {                                 \
    u16* Lp = Bs0 + (bf) * 16384 + (h) * 8192;                   \
    load_lds16(B + bR0 + ((h) ? hB : 0) + (kkv), Lp + dst0);     \
    load_lds16(B + bR1 + ((h) ? hB : 0) + (kkv), Lp + dst1);     \
  } while (0)

  f32x4 acc[2][2][2][4] = {};
  bf16x8 af[2][2], bA[4][2], bB[4][2];

#define MFMA16(QM, QN, BARR)                                                  \
    __builtin_amdgcn_s_setprio(1);                                            \
    _Pragma("unroll") for (int ks = 0; ks < 2; ks++)                          \
      _Pragma("unroll") for (int fm = 0; fm < 2; fm++)                        \
        _Pragma("unroll") for (int fn = 0; fn < 4; fn++)                      \
          acc[QM][QN][fm][fn] = __builtin_amdgcn_mfma_f32_16x16x32_bf16(      \
              af[fm][ks], BARR[fn][ks], acc[QM][QN][fm][fn], 0, 0, 0);        \
    __builtin_amdgcn_s_setprio(0);

#define RD_A(half)                                                            \
    _Pragma("unroll") for (int fm = 0; fm < 2; fm++)                          \
      _Pragma("unroll") for (int ks = 0; ks < 2; ks++)                        \
        af[fm][ks] = rdfrag(half, wm * 32 + fm * 16 + (l & 15), ks, l);
#define RD_B(dstv, half)                                                      \
    _Pragma("unroll") for (int fn = 0; fn < 4; fn++)                          \
      _Pragma("unroll") for (int ks = 0; ks < 2; ks++)                        \
        dstv[fn][ks] = rdfrag(half, wn * 64 + fn * 16 + (l & 15), ks, l);

  // prologue: t0 {Ah0,Bh0,Bh1,Ah1}, t1 {Ah0,Bh0,Bh1}; wait t0 -> vmcnt(3)
  STAGE_A(0, 0, 0); STAGE_B(0, 0, 0); STAGE_B(0, 1, 0); STAGE_A(0, 1, 0);
  if (nkt > 1) { STAGE_A(1, 0, 64); STAGE_B(1, 0, 64); STAGE_B(1, 1, 64); VMCNT3(); }
  else { VMCNT0(); }
  BAR();

  for (int t = 0; t < nkt; ++t) {
    const int cur = t & 1, nxt = cur ^ 1;
    const int kk1 = (t + 1) << 6, kk2 = (t + 2) << 6;
    const bool s1 = (t + 1 < nkt), s2 = (t + 2 < nkt);
    // P1: quadrant (0,0)
    RD_A(As0 + cur * 16384);
    RD_B(bA, Bs0 + cur * 16384);
    if (s1) STAGE_A(nxt, 1, kk1);          // A(t+1)h1 (last of t+1's group)
    BAR(); LGKM0();
    MFMA16(0, 0, bA);
    BAR();
    // P2: (0,1)
    RD_B(bB, Bs0 + cur * 16384 + 8192);
    if (s2) STAGE_A(cur, 0, kk2);          // A(t+2)h0 (slot freed in P1)
    BAR(); LGKM0();
    MFMA16(0, 1, bB);
    BAR();
    // P3: (1,1)
    RD_A(As0 + cur * 16384 + 8192);
    if (s2) STAGE_B(cur, 0, kk2);          // B(t+2)h0 (freed in P1)
    BAR(); LGKM0();
    MFMA16(1, 1, bB);
    BAR();
    // P4: (1,0) — no LDS reads (bA cached)
    if (s2) STAGE_B(cur, 1, kk2);          // B(t+2)h1 (freed in P2)
    BAR();
    MFMA16(1, 0, bA);
    if (s2) { VMCNT3(); } else { VMCNT0(); }
    BAR();
  }
#undef RD_A
#undef RD_B
#undef MFMA16
#undef STAGE_A
#undef STAGE_B

  const int r0c = (l >> 4) << 2;
  if (MODE == G_SC) {
    // packed-causal f32 S: row-block rb stores (rb+1)*256 dense cols
    float* Cb = (float*)Cbase + off.c[z] + (size_t)32768 * rb * (rb + 1);
    const long ldcb = (long)(rb + 1) << 8;
#pragma unroll
    for (int Qn = 0; Qn < 2; Qn++)
#pragma unroll
      for (int fn = 0; fn < 4; fn++) {
        const int col = n0 + Qn * 128 + wn * 64 + fn * 16 + (l & 15);
#pragma unroll
        for (int Qm = 0; Qm < 2; Qm++)
#pragma unroll
          for (int fm = 0; fm < 2; fm++)
#pragma unroll
            for (int r = 0; r < 4; r++) {
              const int row = Qm * 128 + wm * 32 + fm * 16 + r0c + r;
              Cb[(size_t)row * ldcb + col] = acc[Qm][Qn][fm][fn][r];
            }
      }
  } else {
    // LDS-staged coalesced bf16 epilogue (QKV demux / PV -> O)
    __syncthreads();
#pragma unroll
    for (int Qm = 0; Qm < 2; Qm++)
#pragma unroll
      for (int Qn = 0; Qn < 2; Qn++)
#pragma unroll
        for (int fn = 0; fn < 4; fn++) {
          const int coll = Qn * 128 + wn * 64 + fn * 16 + (l & 15);
          const float bv = (MODE == G_QKV) ? bias[n0 + coll] : 0.f;
#pragma unroll
          for (int fm = 0; fm < 2; fm++)
#pragma unroll
            for (int r = 0; r < 4; r++) {
              const int rowl = Qm * 128 + wm * 32 + fm * 16 + r0c + r;
              smem[rowl * 256 + (coll ^ (((rowl >> 2) & 3) << 4))] =
                  bf16bits(acc[Qm][Qn][fm][fn][r] + bv);
            }
        }
    __syncthreads();
    u16* Cb;
    if (MODE == G_QKV) {
      const int sel = n0 >= 4608 ? 2 : (n0 >= 2304 ? 1 : 0);
      Cb = (u16*)Cbase + (size_t)sel * (8192ull * 2304) + (n0 - sel * 2304);
    } else {
      Cb = (u16*)Cbase + off.c[z] + n0;
    }
#pragma unroll
    for (int j = 0; j < 16; j++) {
      const int rowl = j * 16 + (tid >> 5);
      const int c = (tid & 31) * 8;
      bf16x8 v = *(const bf16x8*)&smem[rowl * 256 + (c ^ (((rowl >> 2) & 3) << 4))];
      *(bf16x8*)&Cb[(size_t)(m0 + rowl) * 2304 + c] = v;
    }
  }
}

// ---------------- 128x128 GEMM (4 waves, BK=32, 16KB LDS) — Wo / FF ----------
template<int EPI>
__global__ __launch_bounds__(256) void k_gemm(
    const u16* __restrict__ A, long lda,
    const u16* __restrict__ B, long ldb,
    const float* __restrict__ bias,
    float* __restrict__ C, long ldc, int K)
{
  const int m0 = blockIdx.y * 128, n0 = blockIdx.x * 128;

  __shared__ u16 smem[8192];
  u16* As = smem;
  u16* Bs = smem + 4096;

  const int tid = threadIdx.x;
  const int l = tid & 63;
  const int wr = tid >> 7;
  const int wc = (tid >> 6) & 1;
  const int srow = tid >> 2;
  const int scol = (tid & 3) << 3;

  f32x4 acc[4][4] = {};

  const size_t aoff = (size_t)(m0 + srow) * lda + scol;
  const size_t boff = (size_t)(n0 + srow) * ldb + scol;

  for (int kk = 0; kk < K; kk += 32) {
    __syncthreads();
    load_lds16(A + aoff + kk,            As + (size_t)tid * 8);
    load_lds16(A + aoff + 64 * lda + kk, As + 2048 + (size_t)tid * 8);
    load_lds16(B + boff + kk,            Bs + (size_t)tid * 8);
    load_lds16(B + boff + 64 * ldb + kk, Bs + 2048 + (size_t)tid * 8);
    __syncthreads();

    const int kc = (l >> 4) << 3;
    const int rA = wr * 64 + (l & 15);
    const int rB = wc * 64 + (l & 15);
    bf16x8 af[4], bfr[4];
#pragma unroll
    for (int i = 0; i < 4; i++) {
      af[i]  = *(const bf16x8*)&As[(rA + i * 16) * 32 + kc];
      bfr[i] = *(const bf16x8*)&Bs[(rB + i * 16) * 32 + kc];
    }
#pragma unroll
    for (int mi = 0; mi < 4; mi++)
#pragma unroll
      for (int ni = 0; ni < 4; ni++)
        acc[mi][ni] = __builtin_amdgcn_mfma_f32_16x16x32_bf16(af[mi], bfr[ni], acc[mi][ni], 0, 0, 0);
  }

  const int r0 = m0 + wr * 64 + ((l >> 4) << 2);
  const int c0 = n0 + wc * 64 + (l & 15);
#pragma unroll
  for (int ni = 0; ni < 4; ni++) {
    const int col = c0 + ni * 16;
    const float bv = bias ? bias[col] : 0.f;
#pragma unroll
    for (int mi = 0; mi < 4; mi++) {
#pragma unroll
      for (int r = 0; r < 4; r++) {
        const int row = r0 + mi * 16 + r;
        float v = acc[mi][ni][r] + bv;
        if (EPI == EPI_LEAKY) v = v > 0.f ? v : 0.01f * v;
        C[(size_t)row * ldc + col] = v;
      }
    }
  }
}

// ---------------- helpers ----------------
__global__ __launch_bounds__(256) void k_cast_x(const float* __restrict__ in,
                                                u16* __restrict__ out) {
  const size_t i = ((size_t)blockIdx.x * 256 + threadIdx.x) * 4;
  float4 v = *(const float4*)&in[i];
  ushort4 o;
  o.x = bf16bits(v.x); o.y = bf16bits(v.y); o.z = bf16bits(v.z); o.w = bf16bits(v.w);
  *(ushort4*)&out[i] = o;
}

__global__ __launch_bounds__(256) void k_wt(const float* __restrict__ in,
                                            u16* __restrict__ out, int R, int C) {
  __shared__ float tile[32][33];
  const int c0 = blockIdx.x * 32, r0 = blockIdx.y * 32;
  const int tx = threadIdx.x, ty = threadIdx.y;
#pragma unroll
  for (int k = 0; k < 4; k++)
    tile[ty + 8 * k][tx] = in[(size_t)(r0 + ty + 8 * k) * C + c0 + tx];
  __syncthreads();
#pragma unroll
  for (int k = 0; k < 4; k++)
    out[(size_t)(c0 + ty + 8 * k) * R + r0 + tx] = bf16bits(tile[tx][ty + 8 * k]);
}

__global__ __launch_bounds__(256) void k_bias_concat(const float* __restrict__ bq,
                                                     const float* __restrict__ bk,
                                                     const float* __restrict__ bv,
                                                     float* __restrict__ out) {
  const int i = blockIdx.x * 256 + threadIdx.x;
  if (i < 2304) out[i] = bq[i];
  else if (i < 4608) out[i] = bk[i - 2304];
  else if (i < 6912) out[i] = bv[i - 4608];
}

__global__ __launch_bounds__(256) void k_tv(const u16* __restrict__ V,
                                            u16* __restrict__ Vt) {
  const int bh = blockIdx.z, b = bh / 3, h = bh % 3;
  const int s0 = blockIdx.x * 64, d0 = blockIdx.y * 64;
  __shared__ u16 tile[64][65];
  const int t = threadIdx.x;
  const int tr = t >> 4, tc4 = (t & 15) << 2;
  const u16* src = V + (size_t)(b * 2048 + s0) * 2304 + h * 768 + d0;
#pragma unroll
  for (int p = 0; p < 4; p++) {
    int sr = p * 16 + tr;
    ushort4 v = *(const ushort4*)&src[(size_t)sr * 2304 + tc4];
    tile[sr][tc4] = v.x; tile[sr][tc4 + 1] = v.y; tile[sr][tc4 + 2] = v.z; tile[sr][tc4 + 3] = v.w;
  }
  __syncthreads();
  u16* dst = Vt + (size_t)(bh * 768 + d0) * 2048 + s0;
#pragma unroll
  for (int p = 0; p < 4; p++) {
    int dr = p * 16 + tr;
    ushort4 v;
    v.x = tile[tc4][dr]; v.y = tile[tc4 + 1][dr]; v.z = tile[tc4 + 2][dr]; v.w = tile[tc4 + 3][dr];
    *(ushort4*)&dst[(size_t)dr * 2048 + tc4] = v;
  }
}

// causal row softmax over PACKED S (in place): row i has (rb+1)*256 dense cols
__global__ __launch_bounds__(256) void k_softmax(float* __restrict__ Sc) {
  const int i = blockIdx.x;
  const int rb = i >> 8;
  const int nj = rb + 1;
  const int ldcb = nj << 8;
  const size_t base = (size_t)blockIdx.y * 2359296ull +
                      (size_t)32768 * rb * (rb + 1) + (size_t)(i & 255) * ldcb;
  float* srow = Sc + base;
  u16* prow = (u16*)Sc + base * 2;
  const int t = threadIdx.x;
  float s[8];
  float mx = -1e30f;
#pragma unroll
  for (int j = 0; j < 8; j++) {
    const int col = j * 256 + t;
    float v = -1e30f;
    if (j < nj && col <= i) v = srow[col];
    s[j] = v;
    mx = fmaxf(mx, v);
  }
#pragma unroll
  for (int o = 32; o >= 1; o >>= 1) mx = fmaxf(mx, __shfl_xor(mx, o, 64));
  __shared__ float rmax[4], rsum[4];
  const int w = t >> 6;
  if ((t & 63) == 0) rmax[w] = mx;
  __syncthreads();   // orders all srow reads before P writes below
  mx = fmaxf(fmaxf(rmax[0], rmax[1]), fmaxf(rmax[2], rmax[3]));
  float sum = 0.f;
#pragma unroll
  for (int j = 0; j < 8; j++) {
    const float e = (s[j] > -1e29f) ? expf(s[j] - mx) : 0.f;
    s[j] = e;
    sum += e;
  }
#pragma unroll
  for (int o = 32; o >= 1; o >>= 1) sum += __shfl_xor(sum, o, 64);
  if ((t & 63) == 0) rsum[w] = sum;
  __syncthreads();
  sum = rsum[0] + rsum[1] + rsum[2] + rsum[3];
  const float inv = 1.f / sum;
#pragma unroll
  for (int j = 0; j < 8; j++) {
    const int col = j * 256 + t;
    if (j < nj) prow[col] = bf16bits(s[j] * inv);
  }
}

__global__ __launch_bounds__(256) void k_red1(const float* __restrict__ a,
                                              float* __restrict__ part) {
  float s = 0.f;
  for (size_t idx = (size_t)blockIdx.x * 256 + threadIdx.x; idx < 6291456ull; idx += 2048ull * 256)
    s += a[idx];
#pragma unroll
  for (int o = 32; o >= 1; o >>= 1) s += __shfl_xor(s, o, 64);
  __shared__ float r[4];
  const int t = threadIdx.x, w = t >> 6;
  if ((t & 63) == 0) r[w] = s;
  __syncthreads();
  if (t == 0) part[blockIdx.x] = r[0] + r[1] + r[2] + r[3];
}

__global__ __launch_bounds__(256) void k_red2(const float* __restrict__ part,
                                              float* __restrict__ mean) {
  const int t = threadIdx.x;
  float s = 0.f;
  for (int i = t; i < 2048; i += 256) s += part[i];
#pragma unroll
  for (int o = 32; o >= 1; o >>= 1) s += __shfl_xor(s, o, 64);
  __shared__ float r[4];
  const int w = t >> 6;
  if ((t & 63) == 0) r[w] = s;
  __syncthreads();
  if (t == 0) mean[0] = (r[0] + r[1] + r[2] + r[3]) * (1.f / 6291456.f);
}

__global__ __launch_bounds__(256) void k_residual(const float* __restrict__ a,
                                                  const float* __restrict__ x,
                                                  const float* __restrict__ meanp,
                                                  u16* __restrict__ yb) {
  const float mean = meanp[0];
  const size_t i = ((size_t)blockIdx.x * 256 + threadIdx.x) * 4;
  float4 av = *(const float4*)&a[i];
  float4 xv = *(const float4*)&x[i];
  ushort4 o;
  o.x = bf16bits(av.x - mean + xv.x);
  o.y = bf16bits(av.y - mean + xv.y);
  o.z = bf16bits(av.z - mean + xv.z);
  o.w = bf16bits(av.w - mean + xv.w);
  *(ushort4*)&yb[i] = o;
}

extern "C" void kernel_launch(void* const* d_in, const int* in_sizes, int n_in,
                              void* d_out, int out_size, void* d_ws, size_t ws_size,
                              hipStream_t stream) {
  const float* x   = (const float*)d_in[0];
  const float* Wq  = (const float*)d_in[1];
  const float* bq  = (const float*)d_in[2];
  const float* Wk  = (const float*)d_in[3];
  const float* bk  = (const float*)d_in[4];
  const float* Wv  = (const float*)d_in[5];
  const float* bv  = (const float*)d_in[6];
  const float* Wo  = (const float*)d_in[7];
  const float* bo  = (const float*)d_in[8];
  const float* Wf  = (const float*)d_in[9];
  const float* bfb = (const float*)d_in[10];

  char* ws = (char*)d_ws;
  const size_t o_xb  = 0;
  const size_t o_Wqkvt = 12582912;
  const size_t o_Wot = o_Wqkvt + 10616832;
  const size_t o_Wft = o_Wot + 3538944;
  const size_t o_bqkv = o_Wft + 1179648;
  const size_t o_prt = o_bqkv + 32768;
  const size_t o_mn  = o_prt + 8192;
  const size_t o_Q   = o_mn + 128;
  const size_t MSZ   = 37748736;
  const size_t o_K   = o_Q + MSZ;
  const size_t o_V   = o_K + MSZ;
  const size_t o_Vt  = o_V + MSZ;
  const size_t o_O   = o_Vt + MSZ;
  const size_t o_end = o_O + MSZ;
  const size_t S1    = 9437184;      // packed causal S per head (f32)
  if (ws_size < o_end) return;

  size_t o_Sc; int hpc;
  if (ws_size - o_end >= 12 * S1) { o_Sc = o_end; hpc = 12; }
  else                            { o_Sc = o_V;  hpc = 4; }  // 4*S1 == MSZ (V dead)

  const size_t o_a  = o_Q;
  const size_t o_yb = o_K;

  OffN z0{};
  dim3 b32(32, 8);

  k_cast_x<<<6144, 256, 0, stream>>>(x, (u16*)(ws + o_xb));
  k_wt<<<dim3(72, 24), b32, 0, stream>>>(Wq, (u16*)(ws + o_Wqkvt), 768, 2304);
  k_wt<<<dim3(72, 24), b32, 0, stream>>>(Wk, (u16*)(ws + o_Wqkvt) + 2304 * 768, 768, 2304);
  k_wt<<<dim3(72, 24), b32, 0, stream>>>(Wv, (u16*)(ws + o_Wqkvt) + 2 * 2304 * 768, 768, 2304);
  k_wt<<<dim3(24, 72), b32, 0, stream>>>(Wo, (u16*)(ws + o_Wot), 2304, 768);
  k_wt<<<dim3(24, 24), b32, 0, stream>>>(Wf, (u16*)(ws + o_Wft), 768, 768);
  k_bias_concat<<<27, 256, 0, stream>>>(bq, bk, bv, (float*)(ws + o_bqkv));

  k_g256<G_QKV><<<dim3(27, 32), 512, 0, stream>>>(
      (const u16*)(ws + o_xb), (const u16*)(ws + o_Wqkvt),
      (const float*)(ws + o_bqkv), ws + o_Q, z0);

  k_tv<<<dim3(32, 12, 12), 256, 0, stream>>>((const u16*)(ws + o_V), (u16*)(ws + o_Vt));

  for (int h0 = 0; h0 < 12; h0 += hpc) {
    const int cnt = (12 - h0) < hpc ? (12 - h0) : hpc;
    OffN so{}, po{};
    for (int zz = 0; zz < cnt; zz++) {
      const int bh = h0 + zz, b = bh / 3, h = bh % 3;
      so.a[zz] = (size_t)b * 2048 * 2304 + (size_t)h * 768;
      so.b[zz] = so.a[zz];
      so.c[zz] = (size_t)zz * 2359296;           // packed f32 elems
      po.a[zz] = (size_t)zz * 4718592;           // packed u16 elems (P overlay)
      po.b[zz] = (size_t)bh * 768 * 2048;
      po.c[zz] = (size_t)b * 2048 * 2304 + (size_t)h * 768;
    }
    k_g256<G_SC><<<dim3(8, 8, cnt), 512, 0, stream>>>(
        (const u16*)(ws + o_Q), (const u16*)(ws + o_K), nullptr, ws + o_Sc, so);
    k_softmax<<<dim3(2048, cnt), 256, 0, stream>>>((float*)(ws + o_Sc));
    k_g256<G_PV><<<dim3(3, 8, cnt), 512, 0, stream>>>(
        (const u16*)(ws + o_Sc), (const u16*)(ws + o_Vt), nullptr, ws + o_O, po);
  }

  k_gemm<EPI_F32><<<dim3(6, 64), 256, 0, stream>>>(
      (const u16*)(ws + o_O), 2304, (const u16*)(ws + o_Wot), 2304, bo,
      (float*)(ws + o_a), 768, 2304);

  k_red1<<<2048, 256, 0, stream>>>((const float*)(ws + o_a), (float*)(ws + o_prt));
  k_red2<<<1, 256, 0, stream>>>((const float*)(ws + o_prt), (float*)(ws + o_mn));
  k_residual<<<6144, 256, 0, stream>>>((const float*)(ws + o_a), x,
                                       (const float*)(ws + o_mn), (u16*)(ws + o_yb));

  k_gemm<EPI_LEAKY><<<dim3(6, 64), 256, 0, stream>>>(
      (const u16*)(ws + o_yb), 768, (const u16*)(ws + o_Wft), 768, bfb,
      (float*)d_out, 768, 768);
}

// Round 6
// 543.414 us; speedup vs baseline: 1.2883x; 1.0129x over previous
//
#include <hip/hip_runtime.h>
#include <hip/hip_bf16.h>

typedef __attribute__((ext_vector_type(8))) __bf16 bf16x8;
typedef __attribute__((ext_vector_type(4))) float f32x4;
typedef unsigned short u16;

#define DEV static __device__ __forceinline__

#define BAR() asm volatile("s_barrier" ::: "memory")
#define LGKM0() asm volatile("s_waitcnt lgkmcnt(0)" ::: "memory")
#define VMCNT6() asm volatile("s_waitcnt vmcnt(6)" ::: "memory")
#define VMCNT3() asm volatile("s_waitcnt vmcnt(3)" ::: "memory")
#define VMCNT0() asm volatile("s_waitcnt vmcnt(0)" ::: "memory")

DEV void load_lds16(const void* g, void* l) {
  __builtin_amdgcn_global_load_lds(
      (const __attribute__((address_space(1))) unsigned int*)g,
      (__attribute__((address_space(3))) unsigned int*)l, 16, 0, 0);
}

DEV u16 bf16bits(float v) {
  __hip_bfloat16 h = __float2bfloat16(v);
  return __builtin_bit_cast(u16, h);
}

// swizzled LDS frag read: region rows are 128B; data (row, colbyte) lives at
// colbyte ^ ((row&7)<<4). Row bases are multiples of 16 so row&7 == l&7.
DEV bf16x8 rdfrag(const u16* region, int row, int ks, int l) {
  const int cb = (((ks << 6) | ((l >> 4) << 4)) ^ ((l & 7) << 4));
  return *(const bf16x8*)((const char*)region + row * 128 + cb);
}

struct OffN { unsigned long long a[12], b[12], c[12]; };

enum { G128_SC = 0, G128_PV = 1, G128_PLAIN = 2, G128_LEAKY = 3 };

// ---------------- QKV 256x256 deep-pipelined GEMM (8 waves, BK=64) -----------
__global__ __launch_bounds__(512, 1) void k_qkv256(
    const u16* __restrict__ A, const u16* __restrict__ B,
    const float* __restrict__ bias, u16* __restrict__ C)
{
  int flat = blockIdx.y * 27 + blockIdx.x;       // 864 = 8 * 108, bijective
  flat = (flat & 7) * 108 + (flat >> 3);
  const int n0 = (flat % 27) * 256, m0 = (flat / 27) * 256;
  const int lda = 768, ldb = 768, nkt = 12;

  __shared__ u16 smem[65536];            // As[2][2][8192] | Bs[2][2][8192]
  u16* As0 = smem;
  u16* Bs0 = smem + 32768;

  const int tid = threadIdx.x;
  const int l = tid & 63;
  const int wid = tid >> 6;
  const int wm = wid >> 1, wn = wid & 1;

  const int r0s = wid * 16 + (l >> 3);
  const int ces = ((l & 7) ^ (l >> 3)) << 3;
  const size_t aR0 = (size_t)(m0 + r0s) * lda + ces;
  const size_t aR1 = aR0 + (size_t)8 * lda;
  const size_t bR0 = (size_t)(n0 + r0s) * ldb + ces;
  const size_t bR1 = bR0 + (size_t)8 * ldb;
  const size_t hA = (size_t)128 * lda, hB = (size_t)128 * ldb;
  const int dst0 = wid * 1024 + l * 8, dst1 = dst0 + 512;

#define STAGE_A(bf, h, kkv) do {                                 \
    u16* Lp = As0 + (bf) * 16384 + (h) * 8192;                   \
    load_lds16(A + aR0 + ((h) ? hA : 0) + (kkv), Lp + dst0);     \
    load_lds16(A + aR1 + ((h) ? hA : 0) + (kkv), Lp + dst1);     \
  } while (0)
#define STAGE_B(bf, h, kkv) do {                                 \
    u16* Lp = Bs0 + (bf) * 16384 + (h) * 8192;                   \
    load_lds16(B + bR0 + ((h) ? hB : 0) + (kkv), Lp + dst0);     \
    load_lds16(B + bR1 + ((h) ? hB : 0) + (kkv), Lp + dst1);     \
  } while (0)

  f32x4 acc[2][2][2][4] = {};
  bf16x8 af[2][2], bA[4][2], bB[4][2];

#define MFMA16(QM, QN, BARR)                                                  \
    __builtin_amdgcn_s_setprio(1);                                            \
    _Pragma("unroll") for (int ks = 0; ks < 2; ks++)                          \
      _Pragma("unroll") for (int fm = 0; fm < 2; fm++)                        \
        _Pragma("unroll") for (int fn = 0; fn < 4; fn++)                      \
          acc[QM][QN][fm][fn] = __builtin_amdgcn_mfma_f32_16x16x32_bf16(      \
              af[fm][ks], BARR[fn][ks], acc[QM][QN][fm][fn], 0, 0, 0);        \
    __builtin_amdgcn_s_setprio(0);

#define RD_A(half)                                                            \
    _Pragma("unroll") for (int fm = 0; fm < 2; fm++)                          \
      _Pragma("unroll") for (int ks = 0; ks < 2; ks++)                        \
        af[fm][ks] = rdfrag(half, wm * 32 + fm * 16 + (l & 15), ks, l);
#define RD_B(dstv, half)                                                      \
    _Pragma("unroll") for (int fn = 0; fn < 4; fn++)                          \
      _Pragma("unroll") for (int ks = 0; ks < 2; ks++)                        \
        dstv[fn][ks] = rdfrag(half, wn * 64 + fn * 16 + (l & 15), ks, l);

  STAGE_A(0, 0, 0); STAGE_B(0, 0, 0); STAGE_B(0, 1, 0); STAGE_A(0, 1, 0);
  STAGE_A(1, 0, 64); STAGE_B(1, 0, 64); STAGE_B(1, 1, 64);
  VMCNT3();
  BAR();

  for (int t = 0; t < nkt; ++t) {
    const int cur = t & 1, nxt = cur ^ 1;
    const int kk1 = (t + 1) << 6, kk2 = (t + 2) << 6;
    const bool s1 = (t + 1 < nkt), s2 = (t + 2 < nkt);
    RD_A(As0 + cur * 16384);
    RD_B(bA, Bs0 + cur * 16384);
    if (s1) STAGE_A(nxt, 1, kk1);
    BAR(); LGKM0();
    MFMA16(0, 0, bA);
    BAR();
    RD_B(bB, Bs0 + cur * 16384 + 8192);
    if (s2) STAGE_A(cur, 0, kk2);
    BAR(); LGKM0();
    MFMA16(0, 1, bB);
    BAR();
    RD_A(As0 + cur * 16384 + 8192);
    if (s2) STAGE_B(cur, 0, kk2);
    BAR(); LGKM0();
    MFMA16(1, 1, bB);
    BAR();
    if (s2) STAGE_B(cur, 1, kk2);
    BAR();
    MFMA16(1, 0, bA);
    if (s2) { VMCNT3(); } else { VMCNT0(); }
    BAR();
  }
#undef RD_A
#undef RD_B
#undef MFMA16
#undef STAGE_A
#undef STAGE_B

  __syncthreads();
  const int sel = n0 >= 4608 ? 2 : (n0 >= 2304 ? 1 : 0);
  const int r0c = (l >> 4) << 2;
#pragma unroll
  for (int Qm = 0; Qm < 2; Qm++)
#pragma unroll
    for (int Qn = 0; Qn < 2; Qn++)
#pragma unroll
      for (int fn = 0; fn < 4; fn++) {
        const int coll = Qn * 128 + wn * 64 + fn * 16 + (l & 15);
        const float bv = bias[n0 + coll];
#pragma unroll
        for (int fm = 0; fm < 2; fm++)
#pragma unroll
          for (int r = 0; r < 4; r++) {
            const int rowl = Qm * 128 + wm * 32 + fm * 16 + r0c + r;
            smem[rowl * 256 + (coll ^ (((rowl >> 2) & 3) << 4))] =
                bf16bits(acc[Qm][Qn][fm][fn][r] + bv);
          }
      }
  __syncthreads();
  u16* Cb = C + (size_t)sel * (8192ull * 2304) + (n0 - sel * 2304);
#pragma unroll
  for (int j = 0; j < 16; j++) {
    const int rowl = j * 16 + (tid >> 5);
    const int c = (tid & 31) * 8;
    bf16x8 v = *(const bf16x8*)&smem[rowl * 256 + (c ^ (((rowl >> 2) & 3) << 4))];
    *(bf16x8*)&Cb[(size_t)(m0 + rowl) * 2304 + c] = v;
  }
}

// ---------------- 128x256 engine (8 waves, BK=64, triple-buffer, 1 phase) ----
// Per K-tile: {16 ds_read_b128; stage t+2 (6 loads); BAR; lgkm0; 32 MFMA;
// vmcnt(6); BAR}. Stage t+2 targets buf[(t+2)%3] == buf[(t-1)%3], whose reads
// were sealed by tile t-1's end barrier (rigorous, no heuristic race).
template<int MODE>
__global__ __launch_bounds__(512, 1) void k_g128(
    const u16* __restrict__ Abase, const u16* __restrict__ Bbase,
    const float* __restrict__ bias, void* __restrict__ Cbase,
    long lda, long ldb, long ldc, int K, OffN off)
{
  int m0, n0, z, r = 0, rb = 0, nkt, arow0, brow0;
  const u16 *A, *B;
  if (MODE == G128_SC) {
    r = blockIdx.y; z = blockIdx.z;
    if ((int)blockIdx.x > (r >> 1)) return;
    rb = r >> 1;
    m0 = r * 128; n0 = blockIdx.x * 256;
    nkt = K >> 6;
    A = Abase + off.a[z]; B = Bbase + off.b[z];
    arow0 = m0; brow0 = n0;
  } else if (MODE == G128_PV) {
    r = 15 - (int)blockIdx.y;                  // heavy row-blocks first
    rb = r >> 1;
    z = blockIdx.x / 3;
    m0 = r * 128; n0 = (blockIdx.x % 3) * 256;
    nkt = (rb + 1) * 4;                        // K = (rb+1)*256 (zero-padded)
    lda = (long)(rb + 1) * 512;                // u16 pitch of P overlay rows
    A = Abase + off.a[z] + (size_t)65536 * rb * (rb + 1);
    B = Bbase + off.b[z];
    arow0 = (r & 1) * 128; brow0 = n0;
  } else {
    z = 0;
    m0 = blockIdx.y * 128; n0 = blockIdx.x * 256;
    nkt = K >> 6;
    A = Abase; B = Bbase;
    arow0 = m0; brow0 = n0;
  }

  __shared__ u16 smem[73728];                  // 3 x (A 8192 | B 16384) u16

  const int tid = threadIdx.x;
  const int l = tid & 63;
  const int wid = tid >> 6;
  const int wm = wid & 1;                      // 2 x 64-row slices
  const int wn = wid >> 1;                     // 4 x 64-col slices

  const int ces = ((tid & 7) ^ ((tid >> 3) & 7)) << 3;  // pre-swizzled src col
  const u16* aS = A + (size_t)(arow0 + (tid >> 3)) * lda + ces;
  const u16* bS = B + (size_t)(brow0 + (tid >> 3)) * ldb + ces;
  const int t8 = tid * 8;

#define STG(buf, kkv) do {                                       \
    u16* Lp = smem + (buf) * 24576;                              \
    load_lds16(aS + (kkv),             Lp + t8);                 \
    load_lds16(aS + 64 * lda + (kkv),  Lp + 4096 + t8);          \
    load_lds16(bS + (kkv),             Lp + 8192 + t8);          \
    load_lds16(bS + 64 * ldb + (kkv),  Lp + 12288 + t8);         \
    load_lds16(bS + 128 * ldb + (kkv), Lp + 16384 + t8);         \
    load_lds16(bS + 192 * ldb + (kkv), Lp + 20480 + t8);         \
  } while (0)

  f32x4 acc[4][4] = {};
  bf16x8 af[4][2], bf[4][2];

  STG(0, 0);
  STG(1, 64);
  VMCNT6();
  BAR();

  for (int t = 0; t < nkt; ++t) {
    const u16* Ar = smem + (t % 3) * 24576;
    const u16* Br = Ar + 8192;
#pragma unroll
    for (int fm = 0; fm < 4; fm++)
#pragma unroll
      for (int ks = 0; ks < 2; ks++)
        af[fm][ks] = rdfrag(Ar, wm * 64 + fm * 16 + (l & 15), ks, l);
#pragma unroll
    for (int fn = 0; fn < 4; fn++)
#pragma unroll
      for (int ks = 0; ks < 2; ks++)
        bf[fn][ks] = rdfrag(Br, wn * 64 + fn * 16 + (l & 15), ks, l);
    const bool s2 = (t + 2 < nkt);
    if (s2) STG((t + 2) % 3, (t + 2) << 6);
    BAR(); LGKM0();
    __builtin_amdgcn_s_setprio(1);
#pragma unroll
    for (int ks = 0; ks < 2; ks++)
#pragma unroll
      for (int fm = 0; fm < 4; fm++)
#pragma unroll
        for (int fn = 0; fn < 4; fn++)
          acc[fm][fn] = __builtin_amdgcn_mfma_f32_16x16x32_bf16(
              af[fm][ks], bf[fn][ks], acc[fm][fn], 0, 0, 0);
    __builtin_amdgcn_s_setprio(0);
    if (s2) { VMCNT6(); } else if (t + 1 < nkt) { VMCNT0(); }
    BAR();
  }
#undef STG

  const int r0c = (l >> 4) << 2;
  if (MODE == G128_SC) {
    float* Cb = (float*)Cbase + off.c[z] + (size_t)32768 * rb * (rb + 1);
    const long ldcb = (long)(rb + 1) << 8;
    const int pr0 = (r & 1) * 128;
#pragma unroll
    for (int fn = 0; fn < 4; fn++) {
      const int col = n0 + wn * 64 + fn * 16 + (l & 15);
#pragma unroll
      for (int fm = 0; fm < 4; fm++)
#pragma unroll
        for (int rr = 0; rr < 4; rr++) {
          const int rowl = wm * 64 + fm * 16 + r0c + rr;
          Cb[(size_t)(pr0 + rowl) * ldcb + col] = acc[fm][fn][rr];
        }
    }
  } else if (MODE == G128_PV) {
    __syncthreads();
#pragma unroll
    for (int fn = 0; fn < 4; fn++) {
      const int coll = wn * 64 + fn * 16 + (l & 15);
#pragma unroll
      for (int fm = 0; fm < 4; fm++)
#pragma unroll
        for (int rr = 0; rr < 4; rr++) {
          const int rowl = wm * 64 + fm * 16 + r0c + rr;
          smem[rowl * 256 + (coll ^ (((rowl >> 2) & 3) << 4))] =
              bf16bits(acc[fm][fn][rr]);
        }
    }
    __syncthreads();
    u16* Cb = (u16*)Cbase + off.c[z] + n0;
#pragma unroll
    for (int j = 0; j < 8; j++) {
      const int rowl = j * 16 + (tid >> 5);
      const int c = (tid & 31) * 8;
      bf16x8 v = *(const bf16x8*)&smem[rowl * 256 + (c ^ (((rowl >> 2) & 3) << 4))];
      *(bf16x8*)&Cb[(size_t)(m0 + rowl) * 2304 + c] = v;
    }
  } else {
#pragma unroll
    for (int fn = 0; fn < 4; fn++) {
      const int col = n0 + wn * 64 + fn * 16 + (l & 15);
      const float bv = bias[col];
#pragma unroll
      for (int fm = 0; fm < 4; fm++)
#pragma unroll
        for (int rr = 0; rr < 4; rr++) {
          const int rowl = wm * 64 + fm * 16 + r0c + rr;
          float v = acc[fm][fn][rr] + bv;
          if (MODE == G128_LEAKY) v = v > 0.f ? v : 0.01f * v;
          ((float*)Cbase)[(size_t)(m0 + rowl) * ldc + col] = v;
        }
    }
  }
}

// ---------------- helpers ----------------
__global__ __launch_bounds__(256) void k_cast_x(const float* __restrict__ in,
                                                u16* __restrict__ out) {
  const size_t i = ((size_t)blockIdx.x * 256 + threadIdx.x) * 4;
  float4 v = *(const float4*)&in[i];
  ushort4 o;
  o.x = bf16bits(v.x); o.y = bf16bits(v.y); o.z = bf16bits(v.z); o.w = bf16bits(v.w);
  *(ushort4*)&out[i] = o;
}

__global__ __launch_bounds__(256) void k_wt(const float* __restrict__ in,
                                            u16* __restrict__ out, int R, int C) {
  __shared__ float tile[32][33];
  const int c0 = blockIdx.x * 32, r0 = blockIdx.y * 32;
  const int tx = threadIdx.x, ty = threadIdx.y;
#pragma unroll
  for (int k = 0; k < 4; k++)
    tile[ty + 8 * k][tx] = in[(size_t)(r0 + ty + 8 * k) * C + c0 + tx];
  __syncthreads();
#pragma unroll
  for (int k = 0; k < 4; k++)
    out[(size_t)(c0 + ty + 8 * k) * R + r0 + tx] = bf16bits(tile[tx][ty + 8 * k]);
}

__global__ __launch_bounds__(256) void k_bias_concat(const float* __restrict__ bq,
                                                     const float* __restrict__ bk,
                                                     const float* __restrict__ bv,
                                                     float* __restrict__ out) {
  const int i = blockIdx.x * 256 + threadIdx.x;
  if (i < 2304) out[i] = bq[i];
  else if (i < 4608) out[i] = bk[i - 2304];
  else if (i < 6912) out[i] = bv[i - 4608];
}

__global__ __launch_bounds__(256) void k_tv(const u16* __restrict__ V,
                                            u16* __restrict__ Vt) {
  const int bh = blockIdx.z, b = bh / 3, h = bh % 3;
  const int s0 = blockIdx.x * 64, d0 = blockIdx.y * 64;
  __shared__ u16 tile[64][65];
  const int t = threadIdx.x;
  const int tr = t >> 4, tc4 = (t & 15) << 2;
  const u16* src = V + (size_t)(b * 2048 + s0) * 2304 + h * 768 + d0;
#pragma unroll
  for (int p = 0; p < 4; p++) {
    int sr = p * 16 + tr;
    ushort4 v = *(const ushort4*)&src[(size_t)sr * 2304 + tc4];
    tile[sr][tc4] = v.x; tile[sr][tc4 + 1] = v.y; tile[sr][tc4 + 2] = v.z; tile[sr][tc4 + 3] = v.w;
  }
  __syncthreads();
  u16* dst = Vt + (size_t)(bh * 768 + d0) * 2048 + s0;
#pragma unroll
  for (int p = 0; p < 4; p++) {
    int dr = p * 16 + tr;
    ushort4 v;
    v.x = tile[tc4][dr]; v.y = tile[tc4 + 1][dr]; v.z = tile[tc4 + 2][dr]; v.w = tile[tc4 + 3][dr];
    *(ushort4*)&dst[(size_t)dr * 2048 + tc4] = v;
  }
}

// wave-per-row causal softmax over PACKED S (in place; 4 rows per block).
// 3 passes re-read the row (L2-hot). Overlay safety: at chunk j, prior u16
// writes damaged f32 indices <= (j*64-1)/2 < j*64 <= next read col.
__global__ __launch_bounds__(256) void k_softmax(float* __restrict__ Sc) {
  const int w = threadIdx.x >> 6, l = threadIdx.x & 63;
  const int i = blockIdx.x * 4 + w;
  const int rb = i >> 8;
  const int nj = (rb + 1) * 4;
  const int ldcb = (rb + 1) << 8;
  const size_t base = (size_t)blockIdx.y * 2359296ull +
                      (size_t)32768 * rb * (rb + 1) + (size_t)(i & 255) * ldcb;
  float* srow = Sc + base;
  u16* prow = (u16*)Sc + base * 2;
  float mx = -1e30f;
  for (int j = 0; j < nj; j++) {
    const int col = j * 64 + l;
    if (col <= i) mx = fmaxf(mx, srow[col]);
  }
#pragma unroll
  for (int o = 32; o >= 1; o >>= 1) mx = fmaxf(mx, __shfl_xor(mx, o, 64));
  float sum = 0.f;
  for (int j = 0; j < nj; j++) {
    const int col = j * 64 + l;
    if (col <= i) sum += expf(srow[col] - mx);
  }
#pragma unroll
  for (int o = 32; o >= 1; o >>= 1) sum += __shfl_xor(sum, o, 64);
  const float inv = 1.f / sum;
  for (int j = 0; j < nj; j++) {
    const int col = j * 64 + l;
    const float v = (col <= i) ? expf(srow[col] - mx) * inv : 0.f;
    prow[col] = bf16bits(v);
  }
}

__global__ __launch_bounds__(256) void k_red1(const float* __restrict__ a,
                                              float* __restrict__ part) {
  float s = 0.f;
  for (size_t idx = (size_t)blockIdx.x * 256 + threadIdx.x; idx < 6291456ull; idx += 2048ull * 256)
    s += a[idx];
#pragma unroll
  for (int o = 32; o >= 1; o >>= 1) s += __shfl_xor(s, o, 64);
  __shared__ float r[4];
  const int t = threadIdx.x, w = t >> 6;
  if ((t & 63) == 0) r[w] = s;
  __syncthreads();
  if (t == 0) part[blockIdx.x] = r[0] + r[1] + r[2] + r[3];
}

__global__ __launch_bounds__(256) void k_red2(const float* __restrict__ part,
                                              float* __restrict__ mean) {
  const int t = threadIdx.x;
  float s = 0.f;
  for (int i = t; i < 2048; i += 256) s += part[i];
#pragma unroll
  for (int o = 32; o >= 1; o >>= 1) s += __shfl_xor(s, o, 64);
  __shared__ float r[4];
  const int w = t >> 6;
  if ((t & 63) == 0) r[w] = s;
  __syncthreads();
  if (t == 0) mean[0] = (r[0] + r[1] + r[2] + r[3]) * (1.f / 6291456.f);
}

__global__ __launch_bounds__(256) void k_residual(const float* __restrict__ a,
                                                  const float* __restrict__ x,
                                                  const float* __restrict__ meanp,
                                                  u16* __restrict__ yb) {
  const float mean = meanp[0];
  const size_t i = ((size_t)blockIdx.x * 256 + threadIdx.x) * 4;
  float4 av = *(const float4*)&a[i];
  float4 xv = *(const float4*)&x[i];
  ushort4 o;
  o.x = bf16bits(av.x - mean + xv.x);
  o.y = bf16bits(av.y - mean + xv.y);
  o.z = bf16bits(av.z - mean + xv.z);
  o.w = bf16bits(av.w - mean + xv.w);
  *(ushort4*)&yb[i] = o;
}

extern "C" void kernel_launch(void* const* d_in, const int* in_sizes, int n_in,
                              void* d_out, int out_size, void* d_ws, size_t ws_size,
                              hipStream_t stream) {
  const float* x   = (const float*)d_in[0];
  const float* Wq  = (const float*)d_in[1];
  const float* bq  = (const float*)d_in[2];
  const float* Wk  = (const float*)d_in[3];
  const float* bk  = (const float*)d_in[4];
  const float* Wv  = (const float*)d_in[5];
  const float* bv  = (const float*)d_in[6];
  const float* Wo  = (const float*)d_in[7];
  const float* bo  = (const float*)d_in[8];
  const float* Wf  = (const float*)d_in[9];
  const float* bfb = (const float*)d_in[10];

  char* ws = (char*)d_ws;
  const size_t o_xb  = 0;
  const size_t o_Wqkvt = 12582912;
  const size_t o_Wot = o_Wqkvt + 10616832;
  const size_t o_Wft = o_Wot + 3538944;
  const size_t o_bqkv = o_Wft + 1179648;
  const size_t o_prt = o_bqkv + 32768;
  const size_t o_mn  = o_prt + 8192;
  const size_t o_Q   = o_mn + 128;
  const size_t MSZ   = 37748736;
  const size_t o_K   = o_Q + MSZ;
  const size_t o_V   = o_K + MSZ;
  const size_t o_Vt  = o_V + MSZ;
  const size_t o_O   = o_Vt + MSZ;
  const size_t o_end = o_O + MSZ;
  const size_t S1    = 9437184;      // packed causal S per head (f32)
  if (ws_size < o_end) return;

  size_t o_Sc; int hpc;
  if (ws_size - o_end >= 12 * S1) { o_Sc = o_end; hpc = 12; }
  else                            { o_Sc = o_V;  hpc = 4; }  // V dead after k_tv

  const size_t o_a  = o_Q;
  const size_t o_yb = o_K;

  OffN z0{};
  dim3 b32(32, 8);

  k_cast_x<<<6144, 256, 0, stream>>>(x, (u16*)(ws + o_xb));
  k_wt<<<dim3(72, 24), b32, 0, stream>>>(Wq, (u16*)(ws + o_Wqkvt), 768, 2304);
  k_wt<<<dim3(72, 24), b32, 0, stream>>>(Wk, (u16*)(ws + o_Wqkvt) + 2304 * 768, 768, 2304);
  k_wt<<<dim3(72, 24), b32, 0, stream>>>(Wv, (u16*)(ws + o_Wqkvt) + 2 * 2304 * 768, 768, 2304);
  k_wt<<<dim3(24, 72), b32, 0, stream>>>(Wo, (u16*)(ws + o_Wot), 2304, 768);
  k_wt<<<dim3(24, 24), b32, 0, stream>>>(Wf, (u16*)(ws + o_Wft), 768, 768);
  k_bias_concat<<<27, 256, 0, stream>>>(bq, bk, bv, (float*)(ws + o_bqkv));

  k_qkv256<<<dim3(27, 32), 512, 0, stream>>>(
      (const u16*)(ws + o_xb), (const u16*)(ws + o_Wqkvt),
      (const float*)(ws + o_bqkv), (u16*)(ws + o_Q));

  k_tv<<<dim3(32, 12, 12), 256, 0, stream>>>((const u16*)(ws + o_V), (u16*)(ws + o_Vt));

  for (int h0 = 0; h0 < 12; h0 += hpc) {
    const int cnt = (12 - h0) < hpc ? (12 - h0) : hpc;
    OffN so{}, po{};
    for (int zz = 0; zz < cnt; zz++) {
      const int bh = h0 + zz, b = bh / 3, h = bh % 3;
      so.a[zz] = (size_t)b * 2048 * 2304 + (size_t)h * 768;
      so.b[zz] = so.a[zz];
      so.c[zz] = (size_t)zz * 2359296;           // packed f32 elems
      po.a[zz] = (size_t)zz * 4718592;           // packed u16 elems (P overlay)
      po.b[zz] = (size_t)bh * 768 * 2048;
      po.c[zz] = (size_t)b * 2048 * 2304 + (size_t)h * 768;
    }
    k_g128<G128_SC><<<dim3(8, 16, cnt), 512, 0, stream>>>(
        (const u16*)(ws + o_Q), (const u16*)(ws + o_K), nullptr, ws + o_Sc,
        2304, 2304, 0, 768, so);
    k_softmax<<<dim3(512, cnt), 256, 0, stream>>>((float*)(ws + o_Sc));
    k_g128<G128_PV><<<dim3(3 * cnt, 16), 512, 0, stream>>>(
        (const u16*)(ws + o_Sc), (const u16*)(ws + o_Vt), nullptr, ws + o_O,
        0, 2048, 0, 0, po);
  }

  k_g128<G128_PLAIN><<<dim3(3, 64), 512, 0, stream>>>(
      (const u16*)(ws + o_O), (const u16*)(ws + o_Wot), bo, ws + o_a,
      2304, 2304, 768, 2304, z0);

  k_red1<<<2048, 256, 0, stream>>>((const float*)(ws + o_a), (float*)(ws + o_prt));
  k_red2<<<1, 256, 0, stream>>>((const float*)(ws + o_prt), (float*)(ws + o_mn));
  k_residual<<<6144, 256, 0, stream>>>((const float*)(ws + o_a), x,
                                       (const float*)(ws + o_mn), (u16*)(ws + o_yb));

  k_g128<G128_LEAKY><<<dim3(3, 64), 512, 0, stream>>>(
      (const u16*)(ws + o_yb), (const u16*)(ws + o_Wft), bfb, d_out,
      768, 768, 768, 768, z0);
}

// Round 7
// 436.747 us; speedup vs baseline: 1.6030x; 1.2442x over previous
//
#include <hip/hip_runtime.h>
#include <hip/hip_bf16.h>

typedef __attribute__((ext_vector_type(8))) __bf16 bf16x8;
typedef __attribute__((ext_vector_type(4))) float f32x4;
typedef unsigned short u16;

#define DEV static __device__ __forceinline__

#define BAR() asm volatile("s_barrier" ::: "memory")
#define LGKM0() asm volatile("s_waitcnt lgkmcnt(0)" ::: "memory")
#define VMCNT6() asm volatile("s_waitcnt vmcnt(6)" ::: "memory")
#define VMCNT3() asm volatile("s_waitcnt vmcnt(3)" ::: "memory")
#define VMCNT0() asm volatile("s_waitcnt vmcnt(0)" ::: "memory")

DEV void load_lds16(const void* g, void* l) {
  __builtin_amdgcn_global_load_lds(
      (const __attribute__((address_space(1))) unsigned int*)g,
      (__attribute__((address_space(3))) unsigned int*)l, 16, 0, 0);
}

DEV u16 bf16bits(float v) {
  __hip_bfloat16 h = __float2bfloat16(v);
  return __builtin_bit_cast(u16, h);
}

DEV float bf2f(u16 u) {
  return __builtin_bit_cast(float, (unsigned)u << 16);
}

// swizzled LDS frag read: region rows are 128B; data (row, colbyte) lives at
// colbyte ^ ((row&7)<<4). Row bases are multiples of 16 so row&7 == l&7.
DEV bf16x8 rdfrag(const u16* region, int row, int ks, int l) {
  const int cb = (((ks << 6) | ((l >> 4) << 4)) ^ ((l & 7) << 4));
  return *(const bf16x8*)((const char*)region + row * 128 + cb);
}

struct OffN { unsigned long long a[12], b[12], c[12]; };

enum { G128_SC = 0, G128_PV = 1, G128_PLAIN = 2, G128_LEAKY = 3 };

// ---------------- QKV 256x256 deep-pipelined GEMM (8 waves, BK=64) -----------
// Writes Q|K rows normally; V columns are written TRANSPOSED into Vt.
__global__ __launch_bounds__(512, 1) void k_qkv256(
    const u16* __restrict__ A, const u16* __restrict__ B,
    const float* __restrict__ bias, u16* __restrict__ C, u16* __restrict__ Vt)
{
  int flat = blockIdx.y * 27 + blockIdx.x;       // 864 = 8 * 108, bijective
  flat = (flat & 7) * 108 + (flat >> 3);
  const int n0 = (flat % 27) * 256, m0 = (flat / 27) * 256;
  const int lda = 768, ldb = 768, nkt = 12;

  __shared__ u16 smem[65536];            // As[2][2][8192] | Bs[2][2][8192]
  u16* As0 = smem;
  u16* Bs0 = smem + 32768;

  const int tid = threadIdx.x;
  const int l = tid & 63;
  const int wid = tid >> 6;
  const int wm = wid >> 1, wn = wid & 1;

  const int r0s = wid * 16 + (l >> 3);
  const int ces = ((l & 7) ^ (l >> 3)) << 3;
  const size_t aR0 = (size_t)(m0 + r0s) * lda + ces;
  const size_t aR1 = aR0 + (size_t)8 * lda;
  const size_t bR0 = (size_t)(n0 + r0s) * ldb + ces;
  const size_t bR1 = bR0 + (size_t)8 * ldb;
  const size_t hA = (size_t)128 * lda, hB = (size_t)128 * ldb;
  const int dst0 = wid * 1024 + l * 8, dst1 = dst0 + 512;

#define STAGE_A(bf, h, kkv) do {                                 \
    u16* Lp = As0 + (bf) * 16384 + (h) * 8192;                   \
    load_lds16(A + aR0 + ((h) ? hA : 0) + (kkv), Lp + dst0);     \
    load_lds16(A + aR1 + ((h) ? hA : 0) + (kkv), Lp + dst1);     \
  } while (0)
#define STAGE_B(bf, h, kkv) do {                                 \
    u16* Lp = Bs0 + (bf) * 16384 + (h) * 8192;                   \
    load_lds16(B + bR0 + ((h) ? hB : 0) + (kkv), Lp + dst0);     \
    load_lds16(B + bR1 + ((h) ? hB : 0) + (kkv), Lp + dst1);     \
  } while (0)

  f32x4 acc[2][2][2][4] = {};
  bf16x8 af[2][2], bA[4][2], bB[4][2];

#define MFMA16(QM, QN, BARR)                                                  \
    __builtin_amdgcn_s_setprio(1);                                            \
    _Pragma("unroll") for (int ks = 0; ks < 2; ks++)                          \
      _Pragma("unroll") for (int fm = 0; fm < 2; fm++)                        \
        _Pragma("unroll") for (int fn = 0; fn < 4; fn++)                      \
          acc[QM][QN][fm][fn] = __builtin_amdgcn_mfma_f32_16x16x32_bf16(      \
              af[fm][ks], BARR[fn][ks], acc[QM][QN][fm][fn], 0, 0, 0);        \
    __builtin_amdgcn_s_setprio(0);

#define RD_A(half)                                                            \
    _Pragma("unroll") for (int fm = 0; fm < 2; fm++)                          \
      _Pragma("unroll") for (int ks = 0; ks < 2; ks++)                        \
        af[fm][ks] = rdfrag(half, wm * 32 + fm * 16 + (l & 15), ks, l);
#define RD_B(dstv, half)                                                      \
    _Pragma("unroll") for (int fn = 0; fn < 4; fn++)                          \
      _Pragma("unroll") for (int ks = 0; ks < 2; ks++)                        \
        dstv[fn][ks] = rdfrag(half, wn * 64 + fn * 16 + (l & 15), ks, l);

  STAGE_A(0, 0, 0); STAGE_B(0, 0, 0); STAGE_B(0, 1, 0); STAGE_A(0, 1, 0);
  STAGE_A(1, 0, 64); STAGE_B(1, 0, 64); STAGE_B(1, 1, 64);
  VMCNT3();
  BAR();

  for (int t = 0; t < nkt; ++t) {
    const int cur = t & 1, nxt = cur ^ 1;
    const int kk1 = (t + 1) << 6, kk2 = (t + 2) << 6;
    const bool s1 = (t + 1 < nkt), s2 = (t + 2 < nkt);
    RD_A(As0 + cur * 16384);
    RD_B(bA, Bs0 + cur * 16384);
    if (s1) STAGE_A(nxt, 1, kk1);
    BAR(); LGKM0();
    MFMA16(0, 0, bA);
    BAR();
    RD_B(bB, Bs0 + cur * 16384 + 8192);
    if (s2) STAGE_A(cur, 0, kk2);
    BAR(); LGKM0();
    MFMA16(0, 1, bB);
    BAR();
    RD_A(As0 + cur * 16384 + 8192);
    if (s2) STAGE_B(cur, 0, kk2);
    BAR(); LGKM0();
    MFMA16(1, 1, bB);
    BAR();
    if (s2) STAGE_B(cur, 1, kk2);
    BAR();
    MFMA16(1, 0, bA);
    if (s2) { VMCNT3(); } else { VMCNT0(); }
    BAR();
  }
#undef RD_A
#undef RD_B
#undef MFMA16
#undef STAGE_A
#undef STAGE_B

  __syncthreads();
  const int sel = n0 >= 4608 ? 2 : (n0 >= 2304 ? 1 : 0);
  const int r0c = (l >> 4) << 2;
  if (sel == 2) {
    // V columns: stage TRANSPOSED (smem[col][row]) then write Vt coalesced
#pragma unroll
    for (int Qm = 0; Qm < 2; Qm++)
#pragma unroll
      for (int Qn = 0; Qn < 2; Qn++)
#pragma unroll
        for (int fn = 0; fn < 4; fn++) {
          const int coll = Qn * 128 + wn * 64 + fn * 16 + (l & 15);
          const float bv = bias[n0 + coll];
#pragma unroll
          for (int fm = 0; fm < 2; fm++)
#pragma unroll
            for (int r = 0; r < 4; r++) {
              const int rowl = Qm * 128 + wm * 32 + fm * 16 + r0c + r;
              smem[coll * 256 + (rowl ^ (((coll >> 2) & 3) << 4))] =
                  bf16bits(acc[Qm][Qn][fm][fn][r] + bv);
            }
        }
    __syncthreads();
    const int n0v = n0 - 4608;
    const int h = n0v / 768, d0l = n0v % 768;
    const int b = m0 >> 11, sbase = m0 & 2047;
    u16* Cb = Vt + ((size_t)(b * 3 + h) * 768 + d0l) * 2048 + sbase;
#pragma unroll
    for (int j = 0; j < 16; j++) {
      const int dr = j * 16 + (tid >> 5);      // Vt row (d index)
      const int c = (tid & 31) * 8;            // s chunk
      bf16x8 v = *(const bf16x8*)&smem[dr * 256 + (c ^ (((dr >> 2) & 3) << 4))];
      *(bf16x8*)&Cb[(size_t)dr * 2048 + c] = v;
    }
  } else {
#pragma unroll
    for (int Qm = 0; Qm < 2; Qm++)
#pragma unroll
      for (int Qn = 0; Qn < 2; Qn++)
#pragma unroll
        for (int fn = 0; fn < 4; fn++) {
          const int coll = Qn * 128 + wn * 64 + fn * 16 + (l & 15);
          const float bv = bias[n0 + coll];
#pragma unroll
          for (int fm = 0; fm < 2; fm++)
#pragma unroll
            for (int r = 0; r < 4; r++) {
              const int rowl = Qm * 128 + wm * 32 + fm * 16 + r0c + r;
              smem[rowl * 256 + (coll ^ (((rowl >> 2) & 3) << 4))] =
                  bf16bits(acc[Qm][Qn][fm][fn][r] + bv);
            }
        }
    __syncthreads();
    u16* Cb = C + (size_t)sel * (8192ull * 2304) + (n0 - sel * 2304);
#pragma unroll
    for (int j = 0; j < 16; j++) {
      const int rowl = j * 16 + (tid >> 5);
      const int c = (tid & 31) * 8;
      bf16x8 v = *(const bf16x8*)&smem[rowl * 256 + (c ^ (((rowl >> 2) & 3) << 4))];
      *(bf16x8*)&Cb[(size_t)(m0 + rowl) * 2304 + c] = v;
    }
  }
}

// ---------------- 128x256 engine (8 waves, BK=64, triple-buffer, 1 phase) ----
// G128_SC: scores + in-epilogue causal mask + tile-softmax partials + packed
//          bf16 P_t store.  G128_PV: packed P x Vt -> O.  PLAIN/LEAKY: f32 out.
template<int MODE>
__global__ __launch_bounds__(512, 1) void k_g128(
    const u16* __restrict__ Abase, const u16* __restrict__ Bbase,
    const float* __restrict__ bias, void* __restrict__ Cbase,
    float* __restrict__ part,
    long lda, long ldb, long ldc, int K, OffN off)
{
  int m0, n0, z, r = 0, rb = 0, nkt, arow0, brow0;
  const u16 *A, *B;
  if (MODE == G128_SC) {
    r = blockIdx.y; z = blockIdx.z;
    rb = r >> 1;
    if ((int)blockIdx.x > rb) return;
    m0 = r * 128; n0 = blockIdx.x * 256;
    nkt = K >> 6;
    A = Abase + off.a[z]; B = Bbase + off.b[z];
    arow0 = m0; brow0 = n0;
  } else if (MODE == G128_PV) {
    r = 15 - (int)blockIdx.y;                  // heavy row-blocks first
    rb = r >> 1;
    z = blockIdx.x / 3;
    m0 = r * 128; n0 = (blockIdx.x % 3) * 256;
    nkt = (rb + 1) * 4;                        // K = (rb+1)*256
    lda = (long)(rb + 1) * 256;                // packed bf16 P pitch
    A = Abase + off.a[z] + (size_t)32768 * rb * (rb + 1);
    B = Bbase + off.b[z];
    arow0 = (r & 1) * 128; brow0 = n0;
  } else {
    z = 0;
    m0 = blockIdx.y * 128; n0 = blockIdx.x * 256;
    nkt = K >> 6;
    A = Abase; B = Bbase;
    arow0 = m0; brow0 = n0;
  }

  __shared__ u16 smem[73728];                  // 3 x (A 8192 | B 16384) u16

  const int tid = threadIdx.x;
  const int l = tid & 63;
  const int wid = tid >> 6;
  const int wm = wid & 1;                      // 2 x 64-row slices
  const int wn = wid >> 1;                     // 4 x 64-col slices

  const int ces = ((tid & 7) ^ ((tid >> 3) & 7)) << 3;  // pre-swizzled src col
  const u16* aS = A + (size_t)(arow0 + (tid >> 3)) * lda + ces;
  const u16* bS = B + (size_t)(brow0 + (tid >> 3)) * ldb + ces;
  const int t8 = tid * 8;

#define STG(buf, kkv) do {                                       \
    u16* Lp = smem + (buf) * 24576;                              \
    load_lds16(aS + (kkv),             Lp + t8);                 \
    load_lds16(aS + 64 * lda + (kkv),  Lp + 4096 + t8);          \
    load_lds16(bS + (kkv),             Lp + 8192 + t8);          \
    load_lds16(bS + 64 * ldb + (kkv),  Lp + 12288 + t8);         \
    load_lds16(bS + 128 * ldb + (kkv), Lp + 16384 + t8);         \
    load_lds16(bS + 192 * ldb + (kkv), Lp + 20480 + t8);         \
  } while (0)

  f32x4 acc[4][4] = {};
  bf16x8 af[4][2], bf[4][2];

  STG(0, 0);
  STG(1, 64);
  VMCNT6();
  BAR();

  for (int t = 0; t < nkt; ++t) {
    const u16* Ar = smem + (t % 3) * 24576;
    const u16* Br = Ar + 8192;
#pragma unroll
    for (int fm = 0; fm < 4; fm++)
#pragma unroll
      for (int ks = 0; ks < 2; ks++)
        af[fm][ks] = rdfrag(Ar, wm * 64 + fm * 16 + (l & 15), ks, l);
#pragma unroll
    for (int fn = 0; fn < 4; fn++)
#pragma unroll
      for (int ks = 0; ks < 2; ks++)
        bf[fn][ks] = rdfrag(Br, wn * 64 + fn * 16 + (l & 15), ks, l);
    const bool s2 = (t + 2 < nkt);
    if (s2) STG((t + 2) % 3, (t + 2) << 6);
    BAR(); LGKM0();
    __builtin_amdgcn_s_setprio(1);
#pragma unroll
    for (int ks = 0; ks < 2; ks++)
#pragma unroll
      for (int fm = 0; fm < 4; fm++)
#pragma unroll
        for (int fn = 0; fn < 4; fn++)
          acc[fm][fn] = __builtin_amdgcn_mfma_f32_16x16x32_bf16(
              af[fm][ks], bf[fn][ks], acc[fm][fn], 0, 0, 0);
    __builtin_amdgcn_s_setprio(0);
    if (s2) { VMCNT6(); } else if (t + 1 < nkt) { VMCNT0(); }
    BAR();
  }
#undef STG

  const int r0c = (l >> 4) << 2;
  if (MODE == G128_SC) {
    // ---- causal mask + per-row tile max (in place) ----
    float mx4[4][4], s4[4][4];
#pragma unroll
    for (int fm = 0; fm < 4; fm++)
#pragma unroll
      for (int rr = 0; rr < 4; rr++) {
        const int gi = m0 + wm * 64 + fm * 16 + r0c + rr;
        float mv = -1e30f;
#pragma unroll
        for (int fn = 0; fn < 4; fn++) {
          const int gc = n0 + wn * 64 + fn * 16 + (l & 15);
          float v = (gc <= gi) ? acc[fm][fn][rr] : -1e30f;
          acc[fm][fn][rr] = v;
          mv = fmaxf(mv, v);
        }
        mx4[fm][rr] = mv;
      }
#pragma unroll
    for (int o = 1; o < 16; o <<= 1)
#pragma unroll
      for (int fm = 0; fm < 4; fm++)
#pragma unroll
        for (int rr = 0; rr < 4; rr++)
          mx4[fm][rr] = fmaxf(mx4[fm][rr], __shfl_xor(mx4[fm][rr], o, 64));
    float* redm = (float*)smem;          // [128][4]
    float* reds = redm + 512;            // [128][4]
#pragma unroll
    for (int fm = 0; fm < 4; fm++)
#pragma unroll
      for (int rr = 0; rr < 4; rr++)
        if ((l & 15) == fm * 4 + rr)
          redm[(wm * 64 + fm * 16 + r0c + rr) * 4 + wn] = mx4[fm][rr];
    __syncthreads();
    // ---- tile max, e = exp(s - m_t), per-row partial sums ----
#pragma unroll
    for (int fm = 0; fm < 4; fm++)
#pragma unroll
      for (int rr = 0; rr < 4; rr++) {
        const int rowl = wm * 64 + fm * 16 + r0c + rr;
        f32x4 rm = *(const f32x4*)&redm[rowl * 4];
        const float tm = fmaxf(fmaxf(rm[0], rm[1]), fmaxf(rm[2], rm[3]));
        mx4[fm][rr] = tm;
        float ss = 0.f;
#pragma unroll
        for (int fn = 0; fn < 4; fn++) {
          const float e = expf(acc[fm][fn][rr] - tm);
          acc[fm][fn][rr] = e;
          ss += e;
        }
        s4[fm][rr] = ss;
      }
#pragma unroll
    for (int o = 1; o < 16; o <<= 1)
#pragma unroll
      for (int fm = 0; fm < 4; fm++)
#pragma unroll
        for (int rr = 0; rr < 4; rr++)
          s4[fm][rr] += __shfl_xor(s4[fm][rr], o, 64);
#pragma unroll
    for (int fm = 0; fm < 4; fm++)
#pragma unroll
      for (int rr = 0; rr < 4; rr++)
        if ((l & 15) == fm * 4 + rr)
          reds[(wm * 64 + fm * 16 + r0c + rr) * 4 + wn] = s4[fm][rr];
    __syncthreads();
    // ---- write {m_t, sum_t} partials (one lane per row; wn==0 waves) ----
    if (wn == 0) {
#pragma unroll
      for (int fm = 0; fm < 4; fm++)
#pragma unroll
        for (int rr = 0; rr < 4; rr++)
          if ((l & 15) == fm * 4 + rr) {
            const int rowl = wm * 64 + fm * 16 + r0c + rr;
            f32x4 rs = *(const f32x4*)&reds[rowl * 4];
            float2 pw;
            pw.x = mx4[fm][rr];
            pw.y = rs[0] + rs[1] + rs[2] + rs[3];
            *(float2*)&part[(size_t)z * 32768 +
                            ((size_t)(m0 + rowl) * 8 + blockIdx.x) * 2] = pw;
          }
    }
    __syncthreads();
    // ---- store P_t bf16 packed, coalesced via smem ----
#pragma unroll
    for (int fn = 0; fn < 4; fn++) {
      const int coll = wn * 64 + fn * 16 + (l & 15);
#pragma unroll
      for (int fm = 0; fm < 4; fm++)
#pragma unroll
        for (int rr = 0; rr < 4; rr++) {
          const int rowl = wm * 64 + fm * 16 + r0c + rr;
          smem[rowl * 256 + (coll ^ (((rowl >> 2) & 3) << 4))] =
              bf16bits(acc[fm][fn][rr]);
        }
    }
    __syncthreads();
    u16* Cb = (u16*)Cbase + off.c[z] + (size_t)32768 * rb * (rb + 1);
    const int W = (rb + 1) << 8;
    const int pr0 = (r & 1) * 128;
#pragma unroll
    for (int j = 0; j < 8; j++) {
      const int rowl = j * 16 + (tid >> 5);
      const int c = (tid & 31) * 8;
      bf16x8 v = *(const bf16x8*)&smem[rowl * 256 + (c ^ (((rowl >> 2) & 3) << 4))];
      *(bf16x8*)&Cb[(size_t)(pr0 + rowl) * W + n0 + c] = v;
    }
  } else if (MODE == G128_PV) {
    __syncthreads();
#pragma unroll
    for (int fn = 0; fn < 4; fn++) {
      const int coll = wn * 64 + fn * 16 + (l & 15);
#pragma unroll
      for (int fm = 0; fm < 4; fm++)
#pragma unroll
        for (int rr = 0; rr < 4; rr++) {
          const int rowl = wm * 64 + fm * 16 + r0c + rr;
          smem[rowl * 256 + (coll ^ (((rowl >> 2) & 3) << 4))] =
              bf16bits(acc[fm][fn][rr]);
        }
    }
    __syncthreads();
    u16* Cb = (u16*)Cbase + off.c[z] + n0;
#pragma unroll
    for (int j = 0; j < 8; j++) {
      const int rowl = j * 16 + (tid >> 5);
      const int c = (tid & 31) * 8;
      bf16x8 v = *(const bf16x8*)&smem[rowl * 256 + (c ^ (((rowl >> 2) & 3) << 4))];
      *(bf16x8*)&Cb[(size_t)(m0 + rowl) * 2304 + c] = v;
    }
  } else {
#pragma unroll
    for (int fn = 0; fn < 4; fn++) {
      const int col = n0 + wn * 64 + fn * 16 + (l & 15);
      const float bv = bias[col];
#pragma unroll
      for (int fm = 0; fm < 4; fm++)
#pragma unroll
        for (int rr = 0; rr < 4; rr++) {
          const int rowl = wm * 64 + fm * 16 + r0c + rr;
          float v = acc[fm][fn][rr] + bv;
          if (MODE == G128_LEAKY) v = v > 0.f ? v : 0.01f * v;
          ((float*)Cbase)[(size_t)(m0 + rowl) * ldc + col] = v;
        }
    }
  }
}

// ---------------- helpers ----------------
__global__ __launch_bounds__(256) void k_cast_x(const float* __restrict__ in,
                                                u16* __restrict__ out) {
  const size_t i = ((size_t)blockIdx.x * 256 + threadIdx.x) * 4;
  float4 v = *(const float4*)&in[i];
  ushort4 o;
  o.x = bf16bits(v.x); o.y = bf16bits(v.y); o.z = bf16bits(v.z); o.w = bf16bits(v.w);
  *(ushort4*)&out[i] = o;
}

__global__ __launch_bounds__(256) void k_wt(const float* __restrict__ in,
                                            u16* __restrict__ out, int R, int C) {
  __shared__ float tile[32][33];
  const int c0 = blockIdx.x * 32, r0 = blockIdx.y * 32;
  const int tx = threadIdx.x, ty = threadIdx.y;
#pragma unroll
  for (int k = 0; k < 4; k++)
    tile[ty + 8 * k][tx] = in[(size_t)(r0 + ty + 8 * k) * C + c0 + tx];
  __syncthreads();
#pragma unroll
  for (int k = 0; k < 4; k++)
    out[(size_t)(c0 + ty + 8 * k) * R + r0 + tx] = bf16bits(tile[tx][ty + 8 * k]);
}

__global__ __launch_bounds__(256) void k_bias_concat(const float* __restrict__ bq,
                                                     const float* __restrict__ bk,
                                                     const float* __restrict__ bv,
                                                     float* __restrict__ out) {
  const int i = blockIdx.x * 256 + threadIdx.x;
  if (i < 2304) out[i] = bq[i];
  else if (i < 4608) out[i] = bk[i - 2304];
  else if (i < 6912) out[i] = bv[i - 4608];
}

// rescale P_t -> exact softmax: P *= exp(m_t - m) / sum. wave-per-row.
__global__ __launch_bounds__(256) void k_rescale(u16* __restrict__ P,
                                                 const float* __restrict__ part) {
  const int w = threadIdx.x >> 6, l = threadIdx.x & 63;
  const int gi = blockIdx.x * 4 + w;
  const int z = blockIdx.y;
  const int rb = gi >> 8;
  const int W = (rb + 1) << 8;
  const float2* pp = (const float2*)part + (size_t)z * 16384 + (size_t)gi * 8;
  float m = -1e30f;
#pragma unroll
  for (int t = 0; t < 8; t++)
    if (t <= rb) m = fmaxf(m, pp[t].x);
  float den = 0.f;
#pragma unroll
  for (int t = 0; t < 8; t++)
    if (t <= rb) den += pp[t].y * expf(pp[t].x - m);
  const float inv = 1.f / den;
  u16* Prow = P + (size_t)z * 2359296 + (size_t)32768 * rb * (rb + 1) +
              (size_t)(gi & 255) * W;
#pragma unroll
  for (int t = 0; t < 8; t++)
    if (t <= rb) {
      const float ft = expf(pp[t].x - m) * inv;
      ushort4 v = *(const ushort4*)&Prow[t * 256 + l * 4];
      v.x = bf16bits(bf2f(v.x) * ft);
      v.y = bf16bits(bf2f(v.y) * ft);
      v.z = bf16bits(bf2f(v.z) * ft);
      v.w = bf16bits(bf2f(v.w) * ft);
      *(ushort4*)&Prow[t * 256 + l * 4] = v;
    }
}

__global__ __launch_bounds__(256) void k_red1(const float* __restrict__ a,
                                              float* __restrict__ part) {
  float s = 0.f;
  for (size_t idx = (size_t)blockIdx.x * 256 + threadIdx.x; idx < 6291456ull; idx += 2048ull * 256)
    s += a[idx];
#pragma unroll
  for (int o = 32; o >= 1; o >>= 1) s += __shfl_xor(s, o, 64);
  __shared__ float r[4];
  const int t = threadIdx.x, w = t >> 6;
  if ((t & 63) == 0) r[w] = s;
  __syncthreads();
  if (t == 0) part[blockIdx.x] = r[0] + r[1] + r[2] + r[3];
}

__global__ __launch_bounds__(256) void k_red2(const float* __restrict__ part,
                                              float* __restrict__ mean) {
  const int t = threadIdx.x;
  float s = 0.f;
  for (int i = t; i < 2048; i += 256) s += part[i];
#pragma unroll
  for (int o = 32; o >= 1; o >>= 1) s += __shfl_xor(s, o, 64);
  __shared__ float r[4];
  const int w = t >> 6;
  if ((t & 63) == 0) r[w] = s;
  __syncthreads();
  if (t == 0) mean[0] = (r[0] + r[1] + r[2] + r[3]) * (1.f / 6291456.f);
}

__global__ __launch_bounds__(256) void k_residual(const float* __restrict__ a,
                                                  const float* __restrict__ x,
                                                  const float* __restrict__ meanp,
                                                  u16* __restrict__ yb) {
  const float mean = meanp[0];
  const size_t i = ((size_t)blockIdx.x * 256 + threadIdx.x) * 4;
  float4 av = *(const float4*)&a[i];
  float4 xv = *(const float4*)&x[i];
  ushort4 o;
  o.x = bf16bits(av.x - mean + xv.x);
  o.y = bf16bits(av.y - mean + xv.y);
  o.z = bf16bits(av.z - mean + xv.z);
  o.w = bf16bits(av.w - mean + xv.w);
  *(ushort4*)&yb[i] = o;
}

extern "C" void kernel_launch(void* const* d_in, const int* in_sizes, int n_in,
                              void* d_out, int out_size, void* d_ws, size_t ws_size,
                              hipStream_t stream) {
  const float* x   = (const float*)d_in[0];
  const float* Wq  = (const float*)d_in[1];
  const float* bq  = (const float*)d_in[2];
  const float* Wk  = (const float*)d_in[3];
  const float* bk  = (const float*)d_in[4];
  const float* Wv  = (const float*)d_in[5];
  const float* bv  = (const float*)d_in[6];
  const float* Wo  = (const float*)d_in[7];
  const float* bo  = (const float*)d_in[8];
  const float* Wf  = (const float*)d_in[9];
  const float* bfb = (const float*)d_in[10];

  char* ws = (char*)d_ws;
  const size_t MSZ    = 37748736;                 // 8192*2304*2
  const size_t o_Wqkvt = 0;                       // 10,616,832
  const size_t o_Wot  = 10616832;                 // 3,538,944
  const size_t o_Wft  = o_Wot + 3538944;          // 1,179,648
  const size_t o_bqkv = o_Wft + 1179648;          // 32,768
  const size_t o_prt  = o_bqkv + 32768;           // 8,192
  const size_t o_mn   = o_prt + 8192;             // 256
  const size_t o_part = o_mn + 256;               // 12*131072 = 1,572,864
  const size_t o_xb   = o_part + 1572864;         // 12,582,912 (xb; later yb)
  const size_t o_Q    = o_xb + 12582912;          // MSZ (Q; later O)
  const size_t o_K    = o_Q + MSZ;                // MSZ (K; later a f32 25MB)
  const size_t o_Vt   = o_K + MSZ;                // MSZ
  const size_t o_P    = o_Vt + MSZ;               // 12*4,718,592 = 56,623,104
  const size_t o_end  = o_P + 56623104;           // ~199.4 MB
  if (ws_size < o_end) return;

  const size_t o_O  = o_Q;   // Q dead after scores
  const size_t o_a  = o_K;   // K dead after scores
  const size_t o_yb = o_xb;  // xb dead after QKV

  OffN z0{};
  dim3 b32(32, 8);

  k_cast_x<<<6144, 256, 0, stream>>>(x, (u16*)(ws + o_xb));
  k_wt<<<dim3(72, 24), b32, 0, stream>>>(Wq, (u16*)(ws + o_Wqkvt), 768, 2304);
  k_wt<<<dim3(72, 24), b32, 0, stream>>>(Wk, (u16*)(ws + o_Wqkvt) + 2304 * 768, 768, 2304);
  k_wt<<<dim3(72, 24), b32, 0, stream>>>(Wv, (u16*)(ws + o_Wqkvt) + 2 * 2304 * 768, 768, 2304);
  k_wt<<<dim3(24, 72), b32, 0, stream>>>(Wo, (u16*)(ws + o_Wot), 2304, 768);
  k_wt<<<dim3(24, 24), b32, 0, stream>>>(Wf, (u16*)(ws + o_Wft), 768, 768);
  k_bias_concat<<<27, 256, 0, stream>>>(bq, bk, bv, (float*)(ws + o_bqkv));

  k_qkv256<<<dim3(27, 32), 512, 0, stream>>>(
      (const u16*)(ws + o_xb), (const u16*)(ws + o_Wqkvt),
      (const float*)(ws + o_bqkv), (u16*)(ws + o_Q), (u16*)(ws + o_Vt));

  // single-chunk attention: all 12 heads
  OffN so{}, po{};
  for (int zz = 0; zz < 12; zz++) {
    const int b = zz / 3, h = zz % 3;
    so.a[zz] = (size_t)b * 2048 * 2304 + (size_t)h * 768;   // Q (u16)
    so.b[zz] = so.a[zz];                                     // K (u16)
    so.c[zz] = (size_t)zz * 2359296;                         // P (u16)
    po.a[zz] = so.c[zz];                                     // P (u16)
    po.b[zz] = (size_t)zz * 768 * 2048;                      // Vt (u16), bh = zz
    po.c[zz] = so.a[zz];                                     // O (u16)
  }
  k_g128<G128_SC><<<dim3(8, 16, 12), 512, 0, stream>>>(
      (const u16*)(ws + o_Q), (const u16*)(ws + o_K), nullptr, ws + o_P,
      (float*)(ws + o_part), 2304, 2304, 0, 768, so);
  k_rescale<<<dim3(512, 12), 256, 0, stream>>>((u16*)(ws + o_P),
                                               (const float*)(ws + o_part));
  k_g128<G128_PV><<<dim3(36, 16), 512, 0, stream>>>(
      (const u16*)(ws + o_P), (const u16*)(ws + o_Vt), nullptr, ws + o_O,
      nullptr, 0, 2048, 0, 0, po);

  k_g128<G128_PLAIN><<<dim3(3, 64), 512, 0, stream>>>(
      (const u16*)(ws + o_O), (const u16*)(ws + o_Wot), bo, ws + o_a,
      nullptr, 2304, 2304, 768, 2304, z0);

  k_red1<<<2048, 256, 0, stream>>>((const float*)(ws + o_a), (float*)(ws + o_prt));
  k_red2<<<1, 256, 0, stream>>>((const float*)(ws + o_prt), (float*)(ws + o_mn));
  k_residual<<<6144, 256, 0, stream>>>((const float*)(ws + o_a), x,
                                       (const float*)(ws + o_mn), (u16*)(ws + o_yb));

  k_g128<G128_LEAKY><<<dim3(3, 64), 512, 0, stream>>>(
      (const u16*)(ws + o_yb), (const u16*)(ws + o_Wft), bfb, d_out,
      nullptr, 768, 768, 768, 768, z0);
}

// Round 8
// 418.345 us; speedup vs baseline: 1.6735x; 1.0440x over previous
//
#include <hip/hip_runtime.h>
#include <hip/hip_bf16.h>

typedef __attribute__((ext_vector_type(8))) __bf16 bf16x8;
typedef __attribute__((ext_vector_type(4))) float f32x4;
typedef unsigned short u16;

#define DEV static __device__ __forceinline__

#define BAR() asm volatile("s_barrier" ::: "memory")
#define LGKM0() asm volatile("s_waitcnt lgkmcnt(0)" ::: "memory")
#define VMCNT3() asm volatile("s_waitcnt vmcnt(3)" ::: "memory")
#define VMCNT0() asm volatile("s_waitcnt vmcnt(0)" ::: "memory")

DEV void load_lds16(const void* g, void* l) {
  __builtin_amdgcn_global_load_lds(
      (const __attribute__((address_space(1))) unsigned int*)g,
      (__attribute__((address_space(3))) unsigned int*)l, 16, 0, 0);
}

DEV u16 bf16bits(float v) {
  __hip_bfloat16 h = __float2bfloat16(v);
  return __builtin_bit_cast(u16, h);
}

DEV float bf2f(u16 u) {
  return __builtin_bit_cast(float, (unsigned)u << 16);
}

// BK=64 swizzled frag read (rows 128B, 16B-chunk XOR with row&7 bits 0..2 -> <<4)
DEV bf16x8 rdfrag(const u16* region, int row, int ks, int l) {
  const int cb = (((ks << 6) | ((l >> 4) << 4)) ^ ((l & 7) << 4));
  return *(const bf16x8*)((const char*)region + row * 128 + cb);
}

// BK=32 swizzled frag read (rows 64B, chunk c in 0..3 stored at c ^ (row&3))
DEV bf16x8 rdfrag32(const u16* region, int row, int l) {
  const int cb = (((l >> 4) ^ (row & 3)) << 4);
  return *(const bf16x8*)((const char*)region + row * 64 + cb);
}

struct OffN { unsigned long long a[12], b[12], c[12]; };

enum { G128_SC = 0, G128_PV = 1, G128_PLAIN = 2, G128_LEAKY = 3 };

// ---------------- QKV 256x256 deep-pipelined GEMM (8 waves, BK=64) -----------
// Writes Q|K rows normally; V columns are written TRANSPOSED into Vt.
__global__ __launch_bounds__(512, 1) void k_qkv256(
    const u16* __restrict__ A, const u16* __restrict__ B,
    const float* __restrict__ bias, u16* __restrict__ C, u16* __restrict__ Vt)
{
  int flat = blockIdx.y * 27 + blockIdx.x;       // 864 = 8 * 108, bijective
  flat = (flat & 7) * 108 + (flat >> 3);
  const int n0 = (flat % 27) * 256, m0 = (flat / 27) * 256;
  const int lda = 768, ldb = 768, nkt = 12;

  __shared__ u16 smem[65536];            // As[2][2][8192] | Bs[2][2][8192]
  u16* As0 = smem;
  u16* Bs0 = smem + 32768;

  const int tid = threadIdx.x;
  const int l = tid & 63;
  const int wid = tid >> 6;
  const int wm = wid >> 1, wn = wid & 1;

  const int r0s = wid * 16 + (l >> 3);
  const int ces = ((l & 7) ^ (l >> 3)) << 3;
  const size_t aR0 = (size_t)(m0 + r0s) * lda + ces;
  const size_t aR1 = aR0 + (size_t)8 * lda;
  const size_t bR0 = (size_t)(n0 + r0s) * ldb + ces;
  const size_t bR1 = bR0 + (size_t)8 * ldb;
  const size_t hA = (size_t)128 * lda, hB = (size_t)128 * ldb;
  const int dst0 = wid * 1024 + l * 8, dst1 = dst0 + 512;

#define STAGE_A(bf, h, kkv) do {                                 \
    u16* Lp = As0 + (bf) * 16384 + (h) * 8192;                   \
    load_lds16(A + aR0 + ((h) ? hA : 0) + (kkv), Lp + dst0);     \
    load_lds16(A + aR1 + ((h) ? hA : 0) + (kkv), Lp + dst1);     \
  } while (0)
#define STAGE_B(bf, h, kkv) do {                                 \
    u16* Lp = Bs0 + (bf) * 16384 + (h) * 8192;                   \
    load_lds16(B + bR0 + ((h) ? hB : 0) + (kkv), Lp + dst0);     \
    load_lds16(B + bR1 + ((h) ? hB : 0) + (kkv), Lp + dst1);     \
  } while (0)

  f32x4 acc[2][2][2][4] = {};
  bf16x8 af[2][2], bA[4][2], bB[4][2];

#define MFMA16(QM, QN, BARR)                                                  \
    __builtin_amdgcn_s_setprio(1);                                            \
    _Pragma("unroll") for (int ks = 0; ks < 2; ks++)                          \
      _Pragma("unroll") for (int fm = 0; fm < 2; fm++)                        \
        _Pragma("unroll") for (int fn = 0; fn < 4; fn++)                      \
          acc[QM][QN][fm][fn] = __builtin_amdgcn_mfma_f32_16x16x32_bf16(      \
              af[fm][ks], BARR[fn][ks], acc[QM][QN][fm][fn], 0, 0, 0);        \
    __builtin_amdgcn_s_setprio(0);

#define RD_A(half)                                                            \
    _Pragma("unroll") for (int fm = 0; fm < 2; fm++)                          \
      _Pragma("unroll") for (int ks = 0; ks < 2; ks++)                        \
        af[fm][ks] = rdfrag(half, wm * 32 + fm * 16 + (l & 15), ks, l);
#define RD_B(dstv, half)                                                      \
    _Pragma("unroll") for (int fn = 0; fn < 4; fn++)                          \
      _Pragma("unroll") for (int ks = 0; ks < 2; ks++)                        \
        dstv[fn][ks] = rdfrag(half, wn * 64 + fn * 16 + (l & 15), ks, l);

  STAGE_A(0, 0, 0); STAGE_B(0, 0, 0); STAGE_B(0, 1, 0); STAGE_A(0, 1, 0);
  STAGE_A(1, 0, 64); STAGE_B(1, 0, 64); STAGE_B(1, 1, 64);
  VMCNT3();
  BAR();

  for (int t = 0; t < nkt; ++t) {
    const int cur = t & 1, nxt = cur ^ 1;
    const int kk1 = (t + 1) << 6, kk2 = (t + 2) << 6;
    const bool s1 = (t + 1 < nkt), s2 = (t + 2 < nkt);
    RD_A(As0 + cur * 16384);
    RD_B(bA, Bs0 + cur * 16384);
    if (s1) STAGE_A(nxt, 1, kk1);
    BAR(); LGKM0();
    MFMA16(0, 0, bA);
    BAR();
    RD_B(bB, Bs0 + cur * 16384 + 8192);
    if (s2) STAGE_A(cur, 0, kk2);
    BAR(); LGKM0();
    MFMA16(0, 1, bB);
    BAR();
    RD_A(As0 + cur * 16384 + 8192);
    if (s2) STAGE_B(cur, 0, kk2);
    BAR(); LGKM0();
    MFMA16(1, 1, bB);
    BAR();
    if (s2) STAGE_B(cur, 1, kk2);
    BAR();
    MFMA16(1, 0, bA);
    if (s2) { VMCNT3(); } else { VMCNT0(); }
    BAR();
  }
#undef RD_A
#undef RD_B
#undef MFMA16
#undef STAGE_A
#undef STAGE_B

  __syncthreads();
  const int sel = n0 >= 4608 ? 2 : (n0 >= 2304 ? 1 : 0);
  const int r0c = (l >> 4) << 2;
  if (sel == 2) {
    // V columns: stage TRANSPOSED (smem[col][row], 8-u16-chunk XOR swizzle)
#pragma unroll
    for (int Qm = 0; Qm < 2; Qm++)
#pragma unroll
      for (int Qn = 0; Qn < 2; Qn++)
#pragma unroll
        for (int fn = 0; fn < 4; fn++) {
          const int coll = Qn * 128 + wn * 64 + fn * 16 + (l & 15);
          const float bv = bias[n0 + coll];
#pragma unroll
          for (int fm = 0; fm < 2; fm++)
#pragma unroll
            for (int r = 0; r < 4; r++) {
              const int rowl = Qm * 128 + wm * 32 + fm * 16 + r0c + r;
              smem[coll * 256 + ((((rowl >> 3) ^ (coll & 7)) << 3) | (rowl & 7))] =
                  bf16bits(acc[Qm][Qn][fm][fn][r] + bv);
            }
        }
    __syncthreads();
    const int n0v = n0 - 4608;
    const int h = n0v / 768, d0l = n0v % 768;
    const int b = m0 >> 11, sbase = m0 & 2047;
    u16* Cb = Vt + ((size_t)(b * 3 + h) * 768 + d0l) * 2048 + sbase;
#pragma unroll
    for (int j = 0; j < 16; j++) {
      const int dr = j * 16 + (tid >> 5);      // Vt row (d index)
      const int c8 = tid & 31;                 // s chunk (8 u16)
      bf16x8 v = *(const bf16x8*)&smem[dr * 256 + ((c8 ^ (dr & 7)) << 3)];
      *(bf16x8*)&Cb[(size_t)dr * 2048 + c8 * 8] = v;
    }
  } else {
#pragma unroll
    for (int Qm = 0; Qm < 2; Qm++)
#pragma unroll
      for (int Qn = 0; Qn < 2; Qn++)
#pragma unroll
        for (int fn = 0; fn < 4; fn++) {
          const int coll = Qn * 128 + wn * 64 + fn * 16 + (l & 15);
          const float bv = bias[n0 + coll];
#pragma unroll
          for (int fm = 0; fm < 2; fm++)
#pragma unroll
            for (int r = 0; r < 4; r++) {
              const int rowl = Qm * 128 + wm * 32 + fm * 16 + r0c + r;
              smem[rowl * 256 + (coll ^ (((rowl >> 2) & 3) << 4))] =
                  bf16bits(acc[Qm][Qn][fm][fn][r] + bv);
            }
        }
    __syncthreads();
    u16* Cb = C + (size_t)sel * (8192ull * 2304) + (n0 - sel * 2304);
#pragma unroll
    for (int j = 0; j < 16; j++) {
      const int rowl = j * 16 + (tid >> 5);
      const int c = (tid & 31) * 8;
      bf16x8 v = *(const bf16x8*)&smem[rowl * 256 + (c ^ (((rowl >> 2) & 3) << 4))];
      *(bf16x8*)&Cb[(size_t)(m0 + rowl) * 2304 + c] = v;
    }
  }
}

// ---------------- 128x256 engine (8 waves, BK=32, triple-buffer, 72KB LDS) ---
// 2 blocks/CU. Per K-tile: {8 ds_read_b128; stage t+2 (3 loads); BAR; lgkm0;
// 16 MFMA; vmcnt(3); BAR}. Stage t+2 targets buf[(t+2)%3]==buf[(t-1)%3],
// sealed by tile t-1's end barrier.
template<int MODE>
__global__ __launch_bounds__(512, 4) void k_g128(
    const u16* __restrict__ Abase, const u16* __restrict__ Bbase,
    const float* __restrict__ bias, void* __restrict__ Cbase,
    float* __restrict__ part,
    long lda, long ldb, long ldc, int K, OffN off)
{
  int m0, n0, z, r = 0, rb = 0, nkt, arow0, brow0;
  const u16 *A, *B;
  if (MODE == G128_SC) {
    r = blockIdx.y; z = blockIdx.z;
    rb = r >> 1;
    if ((int)blockIdx.x > rb) return;
    m0 = r * 128; n0 = blockIdx.x * 256;
    nkt = K >> 5;
    A = Abase + off.a[z]; B = Bbase + off.b[z];
    arow0 = m0; brow0 = n0;
  } else if (MODE == G128_PV) {
    r = 15 - (int)blockIdx.y;                  // heavy row-blocks first
    rb = r >> 1;
    z = blockIdx.x / 3;
    m0 = r * 128; n0 = (blockIdx.x % 3) * 256;
    nkt = (rb + 1) * 8;                        // K = (rb+1)*256, BK=32
    lda = (long)(rb + 1) * 256;                // packed bf16 P pitch
    A = Abase + off.a[z] + (size_t)32768 * rb * (rb + 1);
    B = Bbase + off.b[z];
    arow0 = (r & 1) * 128; brow0 = n0;
  } else {
    z = 0;
    m0 = blockIdx.y * 128; n0 = blockIdx.x * 256;
    nkt = K >> 5;
    A = Abase; B = Bbase;
    arow0 = m0; brow0 = n0;
  }

  __shared__ u16 smem[36864];                  // 3 x (A 4096 | B 8192) = 72KB

  const int tid = threadIdx.x;
  const int l = tid & 63;
  const int wid = tid >> 6;
  const int wm = wid & 1;                      // 2 x 64-row slices
  const int wn = wid >> 1;                     // 4 x 64-col slices

  const int ces = (((tid & 3) ^ ((tid >> 2) & 3)) << 3);  // pre-swizzled src
  const u16* aS  = A + (size_t)(arow0 + (tid >> 2)) * lda + ces;
  const u16* bS0 = B + (size_t)(brow0 + (tid >> 2)) * ldb + ces;
  const u16* bS1 = bS0 + (size_t)128 * ldb;
  const int t8 = tid * 8;

#define STG(buf, kkv) do {                         \
    u16* Lp = smem + (buf) * 12288;                \
    load_lds16(aS  + (kkv), Lp + t8);              \
    load_lds16(bS0 + (kkv), Lp + 4096 + t8);       \
    load_lds16(bS1 + (kkv), Lp + 8192 + t8);       \
  } while (0)

  f32x4 acc[4][4] = {};
  bf16x8 af[4], bf[4];

  STG(0, 0);
  STG(1, 32);
  VMCNT3();
  BAR();

  for (int t = 0; t < nkt; ++t) {
    const u16* Ar = smem + (t % 3) * 12288;
    const u16* Br = Ar + 4096;
#pragma unroll
    for (int fm = 0; fm < 4; fm++)
      af[fm] = rdfrag32(Ar, wm * 64 + fm * 16 + (l & 15), l);
#pragma unroll
    for (int fn = 0; fn < 4; fn++)
      bf[fn] = rdfrag32(Br, wn * 64 + fn * 16 + (l & 15), l);
    const bool s2 = (t + 2 < nkt);
    if (s2) STG((t + 2) % 3, (t + 2) << 5);
    BAR(); LGKM0();
    __builtin_amdgcn_s_setprio(1);
#pragma unroll
    for (int fm = 0; fm < 4; fm++)
#pragma unroll
      for (int fn = 0; fn < 4; fn++)
        acc[fm][fn] = __builtin_amdgcn_mfma_f32_16x16x32_bf16(
            af[fm], bf[fn], acc[fm][fn], 0, 0, 0);
    __builtin_amdgcn_s_setprio(0);
    if (s2) { VMCNT3(); } else if (t + 1 < nkt) { VMCNT0(); }
    BAR();
  }
#undef STG

  const int r0c = (l >> 4) << 2;
  if (MODE == G128_SC) {
    // ---- causal mask + per-row tile max (in place) ----
    float mx4[4][4], s4[4][4];
#pragma unroll
    for (int fm = 0; fm < 4; fm++)
#pragma unroll
      for (int rr = 0; rr < 4; rr++) {
        const int gi = m0 + wm * 64 + fm * 16 + r0c + rr;
        float mv = -1e30f;
#pragma unroll
        for (int fn = 0; fn < 4; fn++) {
          const int gc = n0 + wn * 64 + fn * 16 + (l & 15);
          float v = (gc <= gi) ? acc[fm][fn][rr] : -1e30f;
          acc[fm][fn][rr] = v;
          mv = fmaxf(mv, v);
        }
        mx4[fm][rr] = mv;
      }
#pragma unroll
    for (int o = 1; o < 16; o <<= 1)
#pragma unroll
      for (int fm = 0; fm < 4; fm++)
#pragma unroll
        for (int rr = 0; rr < 4; rr++)
          mx4[fm][rr] = fmaxf(mx4[fm][rr], __shfl_xor(mx4[fm][rr], o, 64));
    float* redm = (float*)smem;          // [128][4]
    float* reds = redm + 512;            // [128][4]
#pragma unroll
    for (int fm = 0; fm < 4; fm++)
#pragma unroll
      for (int rr = 0; rr < 4; rr++)
        if ((l & 15) == fm * 4 + rr)
          redm[(wm * 64 + fm * 16 + r0c + rr) * 4 + wn] = mx4[fm][rr];
    __syncthreads();
    // ---- tile max, e = exp(s - m_t), per-row partial sums ----
#pragma unroll
    for (int fm = 0; fm < 4; fm++)
#pragma unroll
      for (int rr = 0; rr < 4; rr++) {
        const int rowl = wm * 64 + fm * 16 + r0c + rr;
        f32x4 rm = *(const f32x4*)&redm[rowl * 4];
        const float tm = fmaxf(fmaxf(rm[0], rm[1]), fmaxf(rm[2], rm[3]));
        mx4[fm][rr] = tm;
        float ss = 0.f;
#pragma unroll
        for (int fn = 0; fn < 4; fn++) {
          const float e = __expf(acc[fm][fn][rr] - tm);
          acc[fm][fn][rr] = e;
          ss += e;
        }
        s4[fm][rr] = ss;
      }
#pragma unroll
    for (int o = 1; o < 16; o <<= 1)
#pragma unroll
      for (int fm = 0; fm < 4; fm++)
#pragma unroll
        for (int rr = 0; rr < 4; rr++)
          s4[fm][rr] += __shfl_xor(s4[fm][rr], o, 64);
#pragma unroll
    for (int fm = 0; fm < 4; fm++)
#pragma unroll
      for (int rr = 0; rr < 4; rr++)
        if ((l & 15) == fm * 4 + rr)
          reds[(wm * 64 + fm * 16 + r0c + rr) * 4 + wn] = s4[fm][rr];
    __syncthreads();
    // ---- write {m_t, sum_t} partials (one lane per row; wn==0 waves) ----
    if (wn == 0) {
#pragma unroll
      for (int fm = 0; fm < 4; fm++)
#pragma unroll
        for (int rr = 0; rr < 4; rr++)
          if ((l & 15) == fm * 4 + rr) {
            const int rowl = wm * 64 + fm * 16 + r0c + rr;
            f32x4 rs = *(const f32x4*)&reds[rowl * 4];
            float2 pw;
            pw.x = mx4[fm][rr];
            pw.y = rs[0] + rs[1] + rs[2] + rs[3];
            *(float2*)&part[(size_t)z * 32768 +
                            ((size_t)(m0 + rowl) * 8 + blockIdx.x) * 2] = pw;
          }
    }
    __syncthreads();
    // ---- store P_t bf16 packed, coalesced via smem ----
#pragma unroll
    for (int fn = 0; fn < 4; fn++) {
      const int coll = wn * 64 + fn * 16 + (l & 15);
#pragma unroll
      for (int fm = 0; fm < 4; fm++)
#pragma unroll
        for (int rr = 0; rr < 4; rr++) {
          const int rowl = wm * 64 + fm * 16 + r0c + rr;
          smem[rowl * 256 + (coll ^ (((rowl >> 2) & 3) << 4))] =
              bf16bits(acc[fm][fn][rr]);
        }
    }
    __syncthreads();
    u16* Cb = (u16*)Cbase + off.c[z] + (size_t)32768 * rb * (rb + 1);
    const int W = (rb + 1) << 8;
    const int pr0 = (r & 1) * 128;
#pragma unroll
    for (int j = 0; j < 8; j++) {
      const int rowl = j * 16 + (tid >> 5);
      const int c = (tid & 31) * 8;
      bf16x8 v = *(const bf16x8*)&smem[rowl * 256 + (c ^ (((rowl >> 2) & 3) << 4))];
      *(bf16x8*)&Cb[(size_t)(pr0 + rowl) * W + n0 + c] = v;
    }
  } else if (MODE == G128_PV) {
    __syncthreads();
#pragma unroll
    for (int fn = 0; fn < 4; fn++) {
      const int coll = wn * 64 + fn * 16 + (l & 15);
#pragma unroll
      for (int fm = 0; fm < 4; fm++)
#pragma unroll
        for (int rr = 0; rr < 4; rr++) {
          const int rowl = wm * 64 + fm * 16 + r0c + rr;
          smem[rowl * 256 + (coll ^ (((rowl >> 2) & 3) << 4))] =
              bf16bits(acc[fm][fn][rr]);
        }
    }
    __syncthreads();
    u16* Cb = (u16*)Cbase + off.c[z] + n0;
#pragma unroll
    for (int j = 0; j < 8; j++) {
      const int rowl = j * 16 + (tid >> 5);
      const int c = (tid & 31) * 8;
      bf16x8 v = *(const bf16x8*)&smem[rowl * 256 + (c ^ (((rowl >> 2) & 3) << 4))];
      *(bf16x8*)&Cb[(size_t)(m0 + rowl) * 2304 + c] = v;
    }
  } else {
#pragma unroll
    for (int fn = 0; fn < 4; fn++) {
      const int col = n0 + wn * 64 + fn * 16 + (l & 15);
      const float bv = bias[col];
#pragma unroll
      for (int fm = 0; fm < 4; fm++)
#pragma unroll
        for (int rr = 0; rr < 4; rr++) {
          const int rowl = wm * 64 + fm * 16 + r0c + rr;
          float v = acc[fm][fn][rr] + bv;
          if (MODE == G128_LEAKY) v = v > 0.f ? v : 0.01f * v;
          ((float*)Cbase)[(size_t)(m0 + rowl) * ldc + col] = v;
        }
    }
  }
}

// ---------------- helpers ----------------
__global__ __launch_bounds__(256) void k_cast_x(const float* __restrict__ in,
                                                u16* __restrict__ out) {
  const size_t i = ((size_t)blockIdx.x * 256 + threadIdx.x) * 4;
  float4 v = *(const float4*)&in[i];
  ushort4 o;
  o.x = bf16bits(v.x); o.y = bf16bits(v.y); o.z = bf16bits(v.z); o.w = bf16bits(v.w);
  *(ushort4*)&out[i] = o;
}

__global__ __launch_bounds__(256) void k_wt(const float* __restrict__ in,
                                            u16* __restrict__ out, int R, int C) {
  __shared__ float tile[32][33];
  const int c0 = blockIdx.x * 32, r0 = blockIdx.y * 32;
  const int tx = threadIdx.x, ty = threadIdx.y;
#pragma unroll
  for (int k = 0; k < 4; k++)
    tile[ty + 8 * k][tx] = in[(size_t)(r0 + ty + 8 * k) * C + c0 + tx];
  __syncthreads();
#pragma unroll
  for (int k = 0; k < 4; k++)
    out[(size_t)(c0 + ty + 8 * k) * R + r0 + tx] = bf16bits(tile[tx][ty + 8 * k]);
}

__global__ __launch_bounds__(256) void k_bias_concat(const float* __restrict__ bq,
                                                     const float* __restrict__ bk,
                                                     const float* __restrict__ bv,
                                                     float* __restrict__ out) {
  const int i = blockIdx.x * 256 + threadIdx.x;
  if (i < 2304) out[i] = bq[i];
  else if (i < 4608) out[i] = bk[i - 2304];
  else if (i < 6912) out[i] = bv[i - 4608];
}

// rescale P_t -> exact softmax: P *= exp(m_t - m) / sum. wave-per-row.
__global__ __launch_bounds__(256) void k_rescale(u16* __restrict__ P,
                                                 const float* __restrict__ part) {
  const int w = threadIdx.x >> 6, l = threadIdx.x & 63;
  const int gi = blockIdx.x * 4 + w;
  const int z = blockIdx.y;
  const int rb = gi >> 8;
  const int W = (rb + 1) << 8;
  const float2* pp = (const float2*)part + (size_t)z * 16384 + (size_t)gi * 8;
  float m = -1e30f;
#pragma unroll
  for (int t = 0; t < 8; t++)
    if (t <= rb) m = fmaxf(m, pp[t].x);
  float den = 0.f;
#pragma unroll
  for (int t = 0; t < 8; t++)
    if (t <= rb) den += pp[t].y * __expf(pp[t].x - m);
  const float inv = 1.f / den;
  u16* Prow = P + (size_t)z * 2359296 + (size_t)32768 * rb * (rb + 1) +
              (size_t)(gi & 255) * W;
#pragma unroll
  for (int t = 0; t < 8; t++)
    if (t <= rb) {
      const float ft = __expf(pp[t].x - m) * inv;
      ushort4 v = *(const ushort4*)&Prow[t * 256 + l * 4];
      v.x = bf16bits(bf2f(v.x) * ft);
      v.y = bf16bits(bf2f(v.y) * ft);
      v.z = bf16bits(bf2f(v.z) * ft);
      v.w = bf16bits(bf2f(v.w) * ft);
      *(ushort4*)&Prow[t * 256 + l * 4] = v;
    }
}

__global__ __launch_bounds__(256) void k_red1(const float* __restrict__ a,
                                              float* __restrict__ part) {
  float s = 0.f;
  for (size_t idx = (size_t)blockIdx.x * 256 + threadIdx.x; idx < 6291456ull; idx += 2048ull * 256)
    s += a[idx];
#pragma unroll
  for (int o = 32; o >= 1; o >>= 1) s += __shfl_xor(s, o, 64);
  __shared__ float r[4];
  const int t = threadIdx.x, w = t >> 6;
  if ((t & 63) == 0) r[w] = s;
  __syncthreads();
  if (t == 0) part[blockIdx.x] = r[0] + r[1] + r[2] + r[3];
}

__global__ __launch_bounds__(256) void k_red2(const float* __restrict__ part,
                                              float* __restrict__ mean) {
  const int t = threadIdx.x;
  float s = 0.f;
  for (int i = t; i < 2048; i += 256) s += part[i];
#pragma unroll
  for (int o = 32; o >= 1; o >>= 1) s += __shfl_xor(s, o, 64);
  __shared__ float r[4];
  const int w = t >> 6;
  if ((t & 63) == 0) r[w] = s;
  __syncthreads();
  if (t == 0) mean[0] = (r[0] + r[1] + r[2] + r[3]) * (1.f / 6291456.f);
}

__global__ __launch_bounds__(256) void k_residual(const float* __restrict__ a,
                                                  const float* __restrict__ x,
                                                  const float* __restrict__ meanp,
                                                  u16* __restrict__ yb) {
  const float mean = meanp[0];
  const size_t i = ((size_t)blockIdx.x * 256 + threadIdx.x) * 4;
  float4 av = *(const float4*)&a[i];
  float4 xv = *(const float4*)&x[i];
  ushort4 o;
  o.x = bf16bits(av.x - mean + xv.x);
  o.y = bf16bits(av.y - mean + xv.y);
  o.z = bf16bits(av.z - mean + xv.z);
  o.w = bf16bits(av.w - mean + xv.w);
  *(ushort4*)&yb[i] = o;
}

extern "C" void kernel_launch(void* const* d_in, const int* in_sizes, int n_in,
                              void* d_out, int out_size, void* d_ws, size_t ws_size,
                              hipStream_t stream) {
  const float* x   = (const float*)d_in[0];
  const float* Wq  = (const float*)d_in[1];
  const float* bq  = (const float*)d_in[2];
  const float* Wk  = (const float*)d_in[3];
  const float* bk  = (const float*)d_in[4];
  const float* Wv  = (const float*)d_in[5];
  const float* bv  = (const float*)d_in[6];
  const float* Wo  = (const float*)d_in[7];
  const float* bo  = (const float*)d_in[8];
  const float* Wf  = (const float*)d_in[9];
  const float* bfb = (const float*)d_in[10];

  char* ws = (char*)d_ws;
  const size_t MSZ    = 37748736;                 // 8192*2304*2
  const size_t o_Wqkvt = 0;                       // 10,616,832
  const size_t o_Wot  = 10616832;                 // 3,538,944
  const size_t o_Wft  = o_Wot + 3538944;          // 1,179,648
  const size_t o_bqkv = o_Wft + 1179648;          // 32,768
  const size_t o_prt  = o_bqkv + 32768;           // 8,192
  const size_t o_mn   = o_prt + 8192;             // 256
  const size_t o_part = o_mn + 256;               // 12*131072 = 1,572,864
  const size_t o_xb   = o_part + 1572864;         // 12,582,912 (xb; later yb)
  const size_t o_Q    = o_xb + 12582912;          // MSZ (Q; later O)
  const size_t o_K    = o_Q + MSZ;                // MSZ (K; later a f32 25MB)
  const size_t o_Vt   = o_K + MSZ;                // MSZ
  const size_t o_P    = o_Vt + MSZ;               // 12*4,718,592 = 56,623,104
  const size_t o_end  = o_P + 56623104;           // ~199.4 MB
  if (ws_size < o_end) return;

  const size_t o_O  = o_Q;   // Q dead after scores
  const size_t o_a  = o_K;   // K dead after scores
  const size_t o_yb = o_xb;  // xb dead after QKV

  OffN z0{};
  dim3 b32(32, 8);

  k_cast_x<<<6144, 256, 0, stream>>>(x, (u16*)(ws + o_xb));
  k_wt<<<dim3(72, 24), b32, 0, stream>>>(Wq, (u16*)(ws + o_Wqkvt), 768, 2304);
  k_wt<<<dim3(72, 24), b32, 0, stream>>>(Wk, (u16*)(ws + o_Wqkvt) + 2304 * 768, 768, 2304);
  k_wt<<<dim3(72, 24), b32, 0, stream>>>(Wv, (u16*)(ws + o_Wqkvt) + 2 * 2304 * 768, 768, 2304);
  k_wt<<<dim3(24, 72), b32, 0, stream>>>(Wo, (u16*)(ws + o_Wot), 2304, 768);
  k_wt<<<dim3(24, 24), b32, 0, stream>>>(Wf, (u16*)(ws + o_Wft), 768, 768);
  k_bias_concat<<<27, 256, 0, stream>>>(bq, bk, bv, (float*)(ws + o_bqkv));

  k_qkv256<<<dim3(27, 32), 512, 0, stream>>>(
      (const u16*)(ws + o_xb), (const u16*)(ws + o_Wqkvt),
      (const float*)(ws + o_bqkv), (u16*)(ws + o_Q), (u16*)(ws + o_Vt));

  // single-chunk attention: all 12 heads
  OffN so{}, po{};
  for (int zz = 0; zz < 12; zz++) {
    const int b = zz / 3, h = zz % 3;
    so.a[zz] = (size_t)b * 2048 * 2304 + (size_t)h * 768;   // Q (u16)
    so.b[zz] = so.a[zz];                                     // K (u16)
    so.c[zz] = (size_t)zz * 2359296;                         // P (u16)
    po.a[zz] = so.c[zz];                                     // P (u16)
    po.b[zz] = (size_t)zz * 768 * 2048;                      // Vt (u16), bh = zz
    po.c[zz] = so.a[zz];                                     // O (u16)
  }
  k_g128<G128_SC><<<dim3(8, 16, 12), 512, 0, stream>>>(
      (const u16*)(ws + o_Q), (const u16*)(ws + o_K), nullptr, ws + o_P,
      (float*)(ws + o_part), 2304, 2304, 0, 768, so);
  k_rescale<<<dim3(512, 12), 256, 0, stream>>>((u16*)(ws + o_P),
                                               (const float*)(ws + o_part));
  k_g128<G128_PV><<<dim3(36, 16), 512, 0, stream>>>(
      (const u16*)(ws + o_P), (const u16*)(ws + o_Vt), nullptr, ws + o_O,
      nullptr, 0, 2048, 0, 0, po);

  k_g128<G128_PLAIN><<<dim3(3, 64), 512, 0, stream>>>(
      (const u16*)(ws + o_O), (const u16*)(ws + o_Wot), bo, ws + o_a,
      nullptr, 2304, 2304, 768, 2304, z0);

  k_red1<<<2048, 256, 0, stream>>>((const float*)(ws + o_a), (float*)(ws + o_prt));
  k_red2<<<1, 256, 0, stream>>>((const float*)(ws + o_prt), (float*)(ws + o_mn));
  k_residual<<<6144, 256, 0, stream>>>((const float*)(ws + o_a), x,
                                       (const float*)(ws + o_mn), (u16*)(ws + o_yb));

  k_g128<G128_LEAKY><<<dim3(3, 64), 512, 0, stream>>>(
      (const u16*)(ws + o_yb), (const u16*)(ws + o_Wft), bfb, d_out,
      nullptr, 768, 768, 768, 768, z0);
}